// Round 1
// baseline (735.404 us; speedup 1.0000x reference)
//
#include <hip/hip_runtime.h>
#include <math.h>

#define SCALE 0.17677669529663687f  // 1/sqrt(32)

// ---------------------------------------------------------------------------
// Fused 5-way projection: Y_g = X_g @ W_g + b_g, X in {A,B}, [4096,768]@[768,256]
// grid.x = 20 (5 groups x 4 col-tiles of 64), grid.y = 64 (row tiles of 64)
// 256 threads, 64x64 tile, 4x4 microtile, K-chunks of 16.
// ---------------------------------------------------------------------------
__global__ __launch_bounds__(256) void proj5_kernel(
    const float* __restrict__ A, const float* __restrict__ Bm,
    const float* __restrict__ W0, const float* __restrict__ W1,
    const float* __restrict__ W2, const float* __restrict__ W3,
    const float* __restrict__ W4,
    const float* __restrict__ b0, const float* __restrict__ b1,
    const float* __restrict__ b2, const float* __restrict__ b3,
    const float* __restrict__ b4,
    float* __restrict__ Y0, float* __restrict__ Y1, float* __restrict__ Y2,
    float* __restrict__ Y3, float* __restrict__ Y4)
{
    const int K = 768, N = 256;
    __shared__ float Xs[16][68];   // [k][m]  (transposed)
    __shared__ float Ws[16][68];   // [k][n]

    const int g = blockIdx.x >> 2;
    const float* X = (g == 4) ? Bm : A;
    const float* W; const float* bias; float* Y;
    switch (g) {
        case 0:  W = W0; bias = b0; Y = Y0; break;
        case 1:  W = W1; bias = b1; Y = Y1; break;
        case 2:  W = W2; bias = b2; Y = Y2; break;
        case 3:  W = W3; bias = b3; Y = Y3; break;
        default: W = W4; bias = b4; Y = Y4; break;
    }
    const int bn = (blockIdx.x & 3) * 64;
    const int bm = blockIdx.y * 64;

    const int t  = threadIdx.x;
    const int tx = t & 15, ty = t >> 4;

    float acc[4][4] = {};

    for (int k0 = 0; k0 < K; k0 += 16) {
        // X tile: 64 rows x 16 k.  thread: row = t/4, 4 k's at (t%4)*4
        {
            int row = t >> 2;
            int kp  = (t & 3) * 4;
            float4 v = *(const float4*)&X[(size_t)(bm + row) * K + k0 + kp];
            Xs[kp + 0][row] = v.x; Xs[kp + 1][row] = v.y;
            Xs[kp + 2][row] = v.z; Xs[kp + 3][row] = v.w;
            // W tile: 16 k-rows x 64 n.  thread: krow = t/16, 4 n's at (t%16)*4
            int kr = t >> 4;
            int np = (t & 15) * 4;
            *(float4*)&Ws[kr][np] = *(const float4*)&W[(size_t)(k0 + kr) * N + bn + np];
        }
        __syncthreads();
        #pragma unroll
        for (int kk = 0; kk < 16; ++kk) {
            float4 a = *(const float4*)&Xs[kk][ty * 4];
            float4 b = *(const float4*)&Ws[kk][tx * 4];
            float av[4] = {a.x, a.y, a.z, a.w};
            float bv[4] = {b.x, b.y, b.z, b.w};
            #pragma unroll
            for (int i = 0; i < 4; ++i)
                #pragma unroll
                for (int j = 0; j < 4; ++j)
                    acc[i][j] += av[i] * bv[j];
        }
        __syncthreads();
    }

    float4 bs = *(const float4*)&bias[bn + tx * 4];
    float bvv[4] = {bs.x, bs.y, bs.z, bs.w};
    #pragma unroll
    for (int i = 0; i < 4; ++i) {
        int row = bm + ty * 4 + i;
        float4 r;
        r.x = acc[i][0] + bvv[0];
        r.y = acc[i][1] + bvv[1];
        r.z = acc[i][2] + bvv[2];
        r.w = acc[i][3] + bvv[3];
        *(float4*)&Y[(size_t)row * N + bn + tx * 4] = r;
    }
}

// ---------------------------------------------------------------------------
// Generic tiled GEMM + bias for the final projection: Y = X@W + b
// grid (N/64, M/64), 256 threads.
// ---------------------------------------------------------------------------
__global__ __launch_bounds__(256) void gemm_bias_kernel(
    const float* __restrict__ X, const float* __restrict__ W,
    const float* __restrict__ bias, float* __restrict__ Y,
    int M, int K, int N)
{
    __shared__ float Xs[16][68];
    __shared__ float Ws[16][68];

    const int bn = blockIdx.x * 64;
    const int bm = blockIdx.y * 64;
    const int t  = threadIdx.x;
    const int tx = t & 15, ty = t >> 4;

    float acc[4][4] = {};

    for (int k0 = 0; k0 < K; k0 += 16) {
        {
            int row = t >> 2;
            int kp  = (t & 3) * 4;
            float4 v = *(const float4*)&X[(size_t)(bm + row) * K + k0 + kp];
            Xs[kp + 0][row] = v.x; Xs[kp + 1][row] = v.y;
            Xs[kp + 2][row] = v.z; Xs[kp + 3][row] = v.w;
            int kr = t >> 4;
            int np = (t & 15) * 4;
            *(float4*)&Ws[kr][np] = *(const float4*)&W[(size_t)(k0 + kr) * N + bn + np];
        }
        __syncthreads();
        #pragma unroll
        for (int kk = 0; kk < 16; ++kk) {
            float4 a = *(const float4*)&Xs[kk][ty * 4];
            float4 b = *(const float4*)&Ws[kk][tx * 4];
            float av[4] = {a.x, a.y, a.z, a.w};
            float bv[4] = {b.x, b.y, b.z, b.w};
            #pragma unroll
            for (int i = 0; i < 4; ++i)
                #pragma unroll
                for (int j = 0; j < 4; ++j)
                    acc[i][j] += av[i] * bv[j];
        }
        __syncthreads();
    }

    float4 bs = *(const float4*)&bias[bn + tx * 4];
    float bvv[4] = {bs.x, bs.y, bs.z, bs.w};
    #pragma unroll
    for (int i = 0; i < 4; ++i) {
        int row = bm + ty * 4 + i;
        float4 r;
        r.x = acc[i][0] + bvv[0];
        r.y = acc[i][1] + bvv[1];
        r.z = acc[i][2] + bvv[2];
        r.w = acc[i][3] + bvv[3];
        *(float4*)&Y[(size_t)row * N + bn + tx * 4] = r;
    }
}

// ---------------------------------------------------------------------------
// Flash attention, fp32. Combined logits = (Qs.Ks + Qc.Kc)*SCALE == d=64 QK.
// grid (N/64=32, H=8, B=2), 256 threads.
// Logit phase: thread (ty,tx) computes 4q x 4k; PV phase: thread owns
// 1 query row (t/4) x 8 dims ((t%4)*8). Online softmax state per query row
// held replicated in the logit-phase threads; rescale factor via LDS.
// ---------------------------------------------------------------------------
__global__ __launch_bounds__(256) void attn_kernel(
    const float* __restrict__ Qs, const float* __restrict__ Ks,
    const float* __restrict__ Qc, const float* __restrict__ Kc,
    const float* __restrict__ V,  float* __restrict__ ctx)
{
    __shared__ float Qls[64][68];   // [q][0..31=self | 32..63=cross]
    __shared__ float Kls[64][68];
    __shared__ float Vls[64][36];
    __shared__ float Pls[64][68];
    __shared__ float rowscale[64];
    __shared__ float rowl[64];

    const int t  = threadIdx.x;
    const int tx = t & 15, ty = t >> 4;
    const int b  = blockIdx.z, h = blockIdx.y;
    const int q0 = blockIdx.x * 64;
    const int base = b * 2048;       // row offset into [4096,256]
    const int hc   = h * 32;         // head column offset

    // ---- load Q tile (Qs | Qc), 64 rows x 16 float4 ----
    #pragma unroll
    for (int rep = 0; rep < 4; ++rep) {
        int i = rep * 256 + t;
        int q = i >> 4;
        int f = i & 15;
        const float* src = (f < 8) ? Qs : Qc;
        int fc = (f & 7) * 4;
        float4 v = *(const float4*)&src[(size_t)(base + q0 + q) * 256 + hc + fc];
        *(float4*)&Qls[q][(f < 8 ? 0 : 32) + fc] = v;
    }

    float m_i[4], l_i[4];
    #pragma unroll
    for (int i = 0; i < 4; ++i) { m_i[i] = -INFINITY; l_i[i] = 0.0f; }

    const int qo  = t >> 2;          // PV-phase query row
    const int do0 = (t & 3) * 8;     // PV-phase dim offset
    float O[8] = {};

    for (int k0 = 0; k0 < 2048; k0 += 64) {
        __syncthreads();   // previous PV reads of Kls/Vls/Pls/rowscale complete

        // ---- load K tile (Ks | Kc) ----
        #pragma unroll
        for (int rep = 0; rep < 4; ++rep) {
            int i = rep * 256 + t;
            int kr = i >> 4;
            int f  = i & 15;
            const float* src = (f < 8) ? Ks : Kc;
            int fc = (f & 7) * 4;
            float4 v = *(const float4*)&src[(size_t)(base + k0 + kr) * 256 + hc + fc];
            *(float4*)&Kls[kr][(f < 8 ? 0 : 32) + fc] = v;
        }
        // ---- load V tile: 64 x 32 ----
        #pragma unroll
        for (int rep = 0; rep < 2; ++rep) {
            int i = rep * 256 + t;
            int kr = i >> 3;
            int f  = (i & 7) * 4;
            float4 v = *(const float4*)&V[(size_t)(base + k0 + kr) * 256 + hc + f];
            *(float4*)&Vls[kr][f] = v;
        }
        __syncthreads();

        // ---- logits: 4q x 4k per thread, dot over 64 dims ----
        float s[4][4] = {};
        #pragma unroll
        for (int d = 0; d < 64; d += 4) {
            float4 a4[4], b4[4];
            #pragma unroll
            for (int i = 0; i < 4; ++i) a4[i] = *(const float4*)&Qls[ty * 4 + i][d];
            #pragma unroll
            for (int j = 0; j < 4; ++j) b4[j] = *(const float4*)&Kls[tx * 4 + j][d];
            #pragma unroll
            for (int i = 0; i < 4; ++i) {
                #pragma unroll
                for (int j = 0; j < 4; ++j) {
                    s[i][j] += a4[i].x * b4[j].x + a4[i].y * b4[j].y
                             + a4[i].z * b4[j].z + a4[i].w * b4[j].w;
                }
            }
        }

        // ---- online softmax (per query row, reduced across tx group of 16) ----
        #pragma unroll
        for (int i = 0; i < 4; ++i) {
            float tmax = s[i][0] * SCALE;
            #pragma unroll
            for (int j = 0; j < 4; ++j) { s[i][j] *= SCALE; tmax = fmaxf(tmax, s[i][j]); }
            #pragma unroll
            for (int off = 1; off < 16; off <<= 1)
                tmax = fmaxf(tmax, __shfl_xor(tmax, off, 16));

            float mnew = fmaxf(m_i[i], tmax);
            float sc   = __expf(m_i[i] - mnew);
            float p[4], tsum = 0.0f;
            #pragma unroll
            for (int j = 0; j < 4; ++j) { p[j] = __expf(s[i][j] - mnew); tsum += p[j]; }
            #pragma unroll
            for (int off = 1; off < 16; off <<= 1)
                tsum += __shfl_xor(tsum, off, 16);

            l_i[i] = l_i[i] * sc + tsum;
            m_i[i] = mnew;
            if (tx == 0) rowscale[ty * 4 + i] = sc;
            *(float4*)&Pls[ty * 4 + i][tx * 4] = make_float4(p[0], p[1], p[2], p[3]);
        }
        __syncthreads();

        // ---- PV: O[qo][do0..do0+7] update ----
        float fac = rowscale[qo];
        #pragma unroll
        for (int j = 0; j < 8; ++j) O[j] *= fac;
        #pragma unroll 8
        for (int kk = 0; kk < 64; ++kk) {
            float  pv = Pls[qo][kk];
            float4 v0 = *(const float4*)&Vls[kk][do0];
            float4 v1 = *(const float4*)&Vls[kk][do0 + 4];
            O[0] += pv * v0.x; O[1] += pv * v0.y; O[2] += pv * v0.z; O[3] += pv * v0.w;
            O[4] += pv * v1.x; O[5] += pv * v1.y; O[6] += pv * v1.z; O[7] += pv * v1.w;
        }
    }

    // ---- epilogue: normalize by l, write ctx ----
    if (tx == 0) {
        #pragma unroll
        for (int i = 0; i < 4; ++i) rowl[ty * 4 + i] = l_i[i];
    }
    __syncthreads();
    float inv = 1.0f / rowl[qo];
    float4 o0 = make_float4(O[0] * inv, O[1] * inv, O[2] * inv, O[3] * inv);
    float4 o1 = make_float4(O[4] * inv, O[5] * inv, O[6] * inv, O[7] * inv);
    size_t orow = (size_t)(base + q0 + qo) * 256 + hc + do0;
    *(float4*)&ctx[orow]     = o0;
    *(float4*)&ctx[orow + 4] = o1;
}

// ---------------------------------------------------------------------------
extern "C" void kernel_launch(void* const* d_in, const int* in_sizes, int n_in,
                              void* d_out, int out_size, void* d_ws, size_t ws_size,
                              hipStream_t stream) {
    const float* A     = (const float*)d_in[0];
    const float* B     = (const float*)d_in[1];
    const float* Wq_aa = (const float*)d_in[2];
    const float* bq_aa = (const float*)d_in[3];
    const float* Wk_aa = (const float*)d_in[4];
    const float* bk_aa = (const float*)d_in[5];
    const float* Wv_a  = (const float*)d_in[6];
    const float* bv_a  = (const float*)d_in[7];
    const float* Wk_ab = (const float*)d_in[8];
    const float* bk_ab = (const float*)d_in[9];
    const float* Wq_bb = (const float*)d_in[10];
    const float* bq_bb = (const float*)d_in[11];
    const float* Wo    = (const float*)d_in[12];
    const float* bo    = (const float*)d_in[13];
    float* out = (float*)d_out;

    const size_t MSZ = 4096ull * 256;
    float* ws  = (float*)d_ws;
    float* Qs  = ws;            // Q_self   = A@Wq_aa + bq_aa
    float* Ks  = ws + 1 * MSZ;  // K_self   = A@Wk_aa + bk_aa
    float* Vp  = ws + 2 * MSZ;  // V        = A@Wv_a  + bv_a
    float* Qc  = ws + 3 * MSZ;  // Q_cross  = A@Wk_ab + bk_ab
    float* Kc  = ws + 4 * MSZ;  // K_cross  = B@Wq_bb + bq_bb
    float* ctx = ws + 5 * MSZ;  // attention output [4096,256]

    dim3 pgrid(20, 64);
    proj5_kernel<<<pgrid, 256, 0, stream>>>(A, B,
        Wq_aa, Wk_aa, Wv_a, Wk_ab, Wq_bb,
        bq_aa, bk_aa, bv_a, bk_ab, bq_bb,
        Qs, Ks, Vp, Qc, Kc);

    dim3 agrid(32, 8, 2);
    attn_kernel<<<agrid, 256, 0, stream>>>(Qs, Ks, Qc, Kc, Vp, ctx);

    dim3 ggrid(4, 64);
    gemm_bias_kernel<<<ggrid, 256, 0, stream>>>(ctx, Wo, bo, out, 4096, 256, 256);
}

// Round 2
// 262.651 us; speedup vs baseline: 2.7999x; 2.7999x over previous
//
#include <hip/hip_runtime.h>
#include <math.h>

#define SCALE 0.17677669529663687f  // 1/sqrt(32)

typedef __attribute__((ext_vector_type(8))) short bf16x8;   // 8 bf16 = 4 VGPRs
typedef __attribute__((ext_vector_type(4))) float f32x4;

#define MFMA16(a, b, c) __builtin_amdgcn_mfma_f32_16x16x32_bf16(a, b, c, 0, 0, 0)

__device__ inline unsigned bf16rne(float x) {
    unsigned u = __float_as_uint(x);
    return (u + 0x7FFFu + ((u >> 16) & 1u)) >> 16;
}
__device__ inline float bf16tof(unsigned h) { return __uint_as_float(h << 16); }

// XOR-swizzled byte address within a tile of 128-byte rows (64 bf16/row)
__device__ inline int swzb(int row, int byteInRow) {
    return row * 128 + (byteInRow ^ ((row & 7) << 4));
}

// ---------------------------------------------------------------------------
// Fused 5-way projection (fp32 vector, unchanged from R1): Y_g = X_g@W_g + b_g
// ---------------------------------------------------------------------------
__global__ __launch_bounds__(256) void proj5_kernel(
    const float* __restrict__ A, const float* __restrict__ Bm,
    const float* __restrict__ W0, const float* __restrict__ W1,
    const float* __restrict__ W2, const float* __restrict__ W3,
    const float* __restrict__ W4,
    const float* __restrict__ b0, const float* __restrict__ b1,
    const float* __restrict__ b2, const float* __restrict__ b3,
    const float* __restrict__ b4,
    float* __restrict__ Y0, float* __restrict__ Y1, float* __restrict__ Y2,
    float* __restrict__ Y3, float* __restrict__ Y4)
{
    const int K = 768, N = 256;
    __shared__ float Xs[16][68];
    __shared__ float Ws[16][68];

    const int g = blockIdx.x >> 2;
    const float* X = (g == 4) ? Bm : A;
    const float* W; const float* bias; float* Y;
    switch (g) {
        case 0:  W = W0; bias = b0; Y = Y0; break;
        case 1:  W = W1; bias = b1; Y = Y1; break;
        case 2:  W = W2; bias = b2; Y = Y2; break;
        case 3:  W = W3; bias = b3; Y = Y3; break;
        default: W = W4; bias = b4; Y = Y4; break;
    }
    const int bn = (blockIdx.x & 3) * 64;
    const int bm = blockIdx.y * 64;
    const int t  = threadIdx.x;
    const int tx = t & 15, ty = t >> 4;

    float acc[4][4] = {};

    for (int k0 = 0; k0 < K; k0 += 16) {
        {
            int row = t >> 2;
            int kp  = (t & 3) * 4;
            float4 v = *(const float4*)&X[(size_t)(bm + row) * K + k0 + kp];
            Xs[kp + 0][row] = v.x; Xs[kp + 1][row] = v.y;
            Xs[kp + 2][row] = v.z; Xs[kp + 3][row] = v.w;
            int kr = t >> 4;
            int np = (t & 15) * 4;
            *(float4*)&Ws[kr][np] = *(const float4*)&W[(size_t)(k0 + kr) * N + bn + np];
        }
        __syncthreads();
        #pragma unroll
        for (int kk = 0; kk < 16; ++kk) {
            float4 a = *(const float4*)&Xs[kk][ty * 4];
            float4 b = *(const float4*)&Ws[kk][tx * 4];
            float av[4] = {a.x, a.y, a.z, a.w};
            float bv[4] = {b.x, b.y, b.z, b.w};
            #pragma unroll
            for (int i = 0; i < 4; ++i)
                #pragma unroll
                for (int j = 0; j < 4; ++j)
                    acc[i][j] += av[i] * bv[j];
        }
        __syncthreads();
    }

    float4 bs = *(const float4*)&bias[bn + tx * 4];
    float bvv[4] = {bs.x, bs.y, bs.z, bs.w};
    #pragma unroll
    for (int i = 0; i < 4; ++i) {
        int row = bm + ty * 4 + i;
        float4 r;
        r.x = acc[i][0] + bvv[0];
        r.y = acc[i][1] + bvv[1];
        r.z = acc[i][2] + bvv[2];
        r.w = acc[i][3] + bvv[3];
        *(float4*)&Y[(size_t)row * N + bn + tx * 4] = r;
    }
}

// ---------------------------------------------------------------------------
// Final projection GEMM (fp32 vector, unchanged from R1)
// ---------------------------------------------------------------------------
__global__ __launch_bounds__(256) void gemm_bias_kernel(
    const float* __restrict__ X, const float* __restrict__ W,
    const float* __restrict__ bias, float* __restrict__ Y,
    int M, int K, int N)
{
    __shared__ float Xs[16][68];
    __shared__ float Ws[16][68];

    const int bn = blockIdx.x * 64;
    const int bm = blockIdx.y * 64;
    const int t  = threadIdx.x;
    const int tx = t & 15, ty = t >> 4;

    float acc[4][4] = {};

    for (int k0 = 0; k0 < K; k0 += 16) {
        {
            int row = t >> 2;
            int kp  = (t & 3) * 4;
            float4 v = *(const float4*)&X[(size_t)(bm + row) * K + k0 + kp];
            Xs[kp + 0][row] = v.x; Xs[kp + 1][row] = v.y;
            Xs[kp + 2][row] = v.z; Xs[kp + 3][row] = v.w;
            int kr = t >> 4;
            int np = (t & 15) * 4;
            *(float4*)&Ws[kr][np] = *(const float4*)&W[(size_t)(k0 + kr) * N + bn + np];
        }
        __syncthreads();
        #pragma unroll
        for (int kk = 0; kk < 16; ++kk) {
            float4 a = *(const float4*)&Xs[kk][ty * 4];
            float4 b = *(const float4*)&Ws[kk][tx * 4];
            float av[4] = {a.x, a.y, a.z, a.w};
            float bv[4] = {b.x, b.y, b.z, b.w};
            #pragma unroll
            for (int i = 0; i < 4; ++i)
                #pragma unroll
                for (int j = 0; j < 4; ++j)
                    acc[i][j] += av[i] * bv[j];
        }
        __syncthreads();
    }

    float4 bs = *(const float4*)&bias[bn + tx * 4];
    float bvv[4] = {bs.x, bs.y, bs.z, bs.w};
    #pragma unroll
    for (int i = 0; i < 4; ++i) {
        int row = bm + ty * 4 + i;
        float4 r;
        r.x = acc[i][0] + bvv[0];
        r.y = acc[i][1] + bvv[1];
        r.z = acc[i][2] + bvv[2];
        r.w = acc[i][3] + bvv[3];
        *(float4*)&Y[(size_t)row * N + bn + tx * 4] = r;
    }
}

// ---------------------------------------------------------------------------
// MFMA flash attention, split-bf16 (hi/lo, 3-MFMA) for fp32-level accuracy.
// Combined logits = (Qs.Ks + Qc.Kc)*SCALE == one d=64 QK (self d 0..31,
// cross d 32..63 concatenated).
// Block = 256 thr = 4 waves; wave w owns 16 q rows. Grid (32, H=8, B=2).
// Fragment pattern = verified m97 gemm_bt: lane l reads 8 consecutive
// inner-dim elems at row (l&15), chunk (l>>4)*8; C/D row=(l>>4)*4+r, col=l&15.
// LDS tiles: 128B rows, XOR swizzle byte^=((row&7)<<4)  (T2, G4).
// ---------------------------------------------------------------------------
__global__ __launch_bounds__(256, 2) void attn_mfma_kernel(
    const float* __restrict__ Qs, const float* __restrict__ Ks,
    const float* __restrict__ Qc, const float* __restrict__ Kc,
    const float* __restrict__ V,  float* __restrict__ ctx)
{
    __shared__ short Khi[64 * 64], Klo[64 * 64];   // [k][d], d: 0..31 self | 32..63 cross
    __shared__ short Vhi[32 * 64], Vlo[32 * 64];   // transposed: [d][k]
    __shared__ short Phi[4][16 * 64], Plo[4][16 * 64];  // per-wave [q][k]

    const int t   = threadIdx.x;
    const int w   = t >> 6, l = t & 63;
    const int l15 = l & 15, lg = l >> 4;
    const int b   = blockIdx.z, h = blockIdx.y;
    const int q0  = blockIdx.x * 64 + w * 16;      // this wave's first q
    const int base = b * 2048;
    const int hc   = h * 32;

    // ---- Q fragments: scaled, split hi/lo, kept in registers ----
    bf16x8 qh[2], ql[2];
    {
        const float* srcs[2] = {Qs, Qc};
        #pragma unroll
        for (int s = 0; s < 2; ++s) {
            const float* p = &srcs[s][(size_t)(base + q0 + l15) * 256 + hc + lg * 8];
            float4 f0 = ((const float4*)p)[0];
            float4 f1 = ((const float4*)p)[1];
            float v[8] = {f0.x, f0.y, f0.z, f0.w, f1.x, f1.y, f1.z, f1.w};
            #pragma unroll
            for (int j = 0; j < 8; ++j) {
                float x = v[j] * SCALE;
                unsigned hb = bf16rne(x);
                qh[s][j] = (short)hb;
                ql[s][j] = (short)bf16rne(x - bf16tof(hb));
            }
        }
    }

    // staging maps
    const int kr  = t >> 2;             // K: row 0..63
    const int kdc = (t & 3) * 16;       // K: 16-d chunk (0,16 self / 32,48 cross)
    const float* ksrc = (kdc < 32) ? Ks : Kc;
    const int kcol = hc + (kdc & 31);
    const int vkp = t >> 3;             // V: k-pair 0..31
    const int vdc = (t & 7) * 4;        // V: 4-d chunk

    float m_i[4] = {-INFINITY, -INFINITY, -INFINITY, -INFINITY};
    float l_i[4] = {0.f, 0.f, 0.f, 0.f};
    f32x4 o0 = {0.f, 0.f, 0.f, 0.f}, o1 = {0.f, 0.f, 0.f, 0.f};

    for (int k0 = 0; k0 < 2048; k0 += 64) {
        __syncthreads();   // all waves done reading previous K/V tiles

        // ---- stage K tile [64][64] bf16 hi/lo, swizzled ----
        {
            const float* p = &ksrc[(size_t)(base + k0 + kr) * 256 + kcol];
            #pragma unroll
            for (int i2 = 0; i2 < 4; ++i2) {
                float4 f = ((const float4*)p)[i2];
                int d0 = kdc + i2 * 4;
                unsigned h0 = bf16rne(f.x), h1 = bf16rne(f.y);
                unsigned h2 = bf16rne(f.z), h3 = bf16rne(f.w);
                *(unsigned*)&Khi[swzb(kr, 2 * d0    ) >> 1] = h0 | (h1 << 16);
                *(unsigned*)&Khi[swzb(kr, 2 * d0 + 4) >> 1] = h2 | (h3 << 16);
                unsigned g0 = bf16rne(f.x - bf16tof(h0)), g1 = bf16rne(f.y - bf16tof(h1));
                unsigned g2 = bf16rne(f.z - bf16tof(h2)), g3 = bf16rne(f.w - bf16tof(h3));
                *(unsigned*)&Klo[swzb(kr, 2 * d0    ) >> 1] = g0 | (g1 << 16);
                *(unsigned*)&Klo[swzb(kr, 2 * d0 + 4) >> 1] = g2 | (g3 << 16);
            }
        }
        // ---- stage V tile transposed [32 d][64 k], bf16 hi/lo, swizzled ----
        {
            const float* p0 = &V[(size_t)(base + k0 + 2 * vkp    ) * 256 + hc + vdc];
            const float* p1 = &V[(size_t)(base + k0 + 2 * vkp + 1) * 256 + hc + vdc];
            float4 a = *(const float4*)p0;
            float4 bq = *(const float4*)p1;
            float av[4] = {a.x, a.y, a.z, a.w}, bv[4] = {bq.x, bq.y, bq.z, bq.w};
            #pragma unroll
            for (int j = 0; j < 4; ++j) {
                int d = vdc + j;
                unsigned ha = bf16rne(av[j]), hb = bf16rne(bv[j]);
                *(unsigned*)&Vhi[swzb(d, 4 * vkp) >> 1] = ha | (hb << 16);
                unsigned la = bf16rne(av[j] - bf16tof(ha)), lb = bf16rne(bv[j] - bf16tof(hb));
                *(unsigned*)&Vlo[swzb(d, 4 * vkp) >> 1] = la | (lb << 16);
            }
        }
        __syncthreads();

        // ---- S = Q @ K^T  (16q x 64k), 4 col-tiles, split-bf16 3-MFMA ----
        f32x4 sa[4] = {{0.f,0.f,0.f,0.f},{0.f,0.f,0.f,0.f},{0.f,0.f,0.f,0.f},{0.f,0.f,0.f,0.f}};
        #pragma unroll
        for (int s = 0; s < 2; ++s) {
            int byteo = s * 64 + lg * 16;
            #pragma unroll
            for (int cj = 0; cj < 4; ++cj) {
                int row = cj * 16 + l15;
                bf16x8 kh = *(const bf16x8*)&Khi[swzb(row, byteo) >> 1];
                bf16x8 kl = *(const bf16x8*)&Klo[swzb(row, byteo) >> 1];
                sa[cj] = MFMA16(qh[s], kh, sa[cj]);
                sa[cj] = MFMA16(ql[s], kh, sa[cj]);
                sa[cj] = MFMA16(qh[s], kl, sa[cj]);
            }
        }

        // ---- online softmax: rows q=(lg*4+r), cols spread over 16-lane group ----
        #pragma unroll
        for (int r = 0; r < 4; ++r) {
            float tmax = fmaxf(fmaxf(sa[0][r], sa[1][r]), fmaxf(sa[2][r], sa[3][r]));
            #pragma unroll
            for (int mk = 1; mk < 16; mk <<= 1)
                tmax = fmaxf(tmax, __shfl_xor(tmax, mk));
            float mnew = fmaxf(m_i[r], tmax);
            float scl  = __expf(m_i[r] - mnew);
            m_i[r] = mnew;
            float tsum = 0.f;
            #pragma unroll
            for (int cj = 0; cj < 4; ++cj) {
                float pv = __expf(sa[cj][r] - mnew);
                sa[cj][r] = pv;
                tsum += pv;
            }
            #pragma unroll
            for (int mk = 1; mk < 16; mk <<= 1)
                tsum += __shfl_xor(tsum, mk);
            l_i[r] = l_i[r] * scl + tsum;
            o0[r] *= scl;
            o1[r] *= scl;
        }

        // ---- write P (split hi/lo) to this wave's LDS buffer ----
        #pragma unroll
        for (int r = 0; r < 4; ++r) {
            #pragma unroll
            for (int cj = 0; cj < 4; ++cj) {
                float pv = sa[cj][r];
                unsigned hb = bf16rne(pv);
                int idx = swzb(lg * 4 + r, 2 * (cj * 16 + l15)) >> 1;
                Phi[w][idx] = (short)hb;
                Plo[w][idx] = (short)bf16rne(pv - bf16tof(hb));
            }
        }
        // wave-internal LDS write->read: DS pipe is in-order per wave; compiler
        // inserts the lgkmcnt before the dependent reads below.

        // ---- O += P @ V  (16q x 32d), split-bf16 3-MFMA ----
        #pragma unroll
        for (int ks = 0; ks < 2; ++ks) {
            int byteo = ks * 64 + lg * 16;
            bf16x8 ph  = *(const bf16x8*)&Phi[w][swzb(l15, byteo) >> 1];
            bf16x8 pl  = *(const bf16x8*)&Plo[w][swzb(l15, byteo) >> 1];
            bf16x8 vh0 = *(const bf16x8*)&Vhi[swzb(l15,      byteo) >> 1];
            bf16x8 vl0 = *(const bf16x8*)&Vlo[swzb(l15,      byteo) >> 1];
            bf16x8 vh1 = *(const bf16x8*)&Vhi[swzb(16 + l15, byteo) >> 1];
            bf16x8 vl1 = *(const bf16x8*)&Vlo[swzb(16 + l15, byteo) >> 1];
            o0 = MFMA16(ph, vh0, o0);
            o0 = MFMA16(pl, vh0, o0);
            o0 = MFMA16(ph, vl0, o0);
            o1 = MFMA16(ph, vh1, o1);
            o1 = MFMA16(pl, vh1, o1);
            o1 = MFMA16(ph, vl1, o1);
        }
    }

    // ---- epilogue: normalize and write ctx ----
    #pragma unroll
    for (int r = 0; r < 4; ++r) {
        float inv = 1.0f / l_i[r];
        size_t orow = (size_t)(base + q0 + lg * 4 + r) * 256 + hc;
        ctx[orow + l15]      = o0[r] * inv;
        ctx[orow + 16 + l15] = o1[r] * inv;
    }
}

// ---------------------------------------------------------------------------
extern "C" void kernel_launch(void* const* d_in, const int* in_sizes, int n_in,
                              void* d_out, int out_size, void* d_ws, size_t ws_size,
                              hipStream_t stream) {
    const float* A     = (const float*)d_in[0];
    const float* B     = (const float*)d_in[1];
    const float* Wq_aa = (const float*)d_in[2];
    const float* bq_aa = (const float*)d_in[3];
    const float* Wk_aa = (const float*)d_in[4];
    const float* bk_aa = (const float*)d_in[5];
    const float* Wv_a  = (const float*)d_in[6];
    const float* bv_a  = (const float*)d_in[7];
    const float* Wk_ab = (const float*)d_in[8];
    const float* bk_ab = (const float*)d_in[9];
    const float* Wq_bb = (const float*)d_in[10];
    const float* bq_bb = (const float*)d_in[11];
    const float* Wo    = (const float*)d_in[12];
    const float* bo    = (const float*)d_in[13];
    float* out = (float*)d_out;

    const size_t MSZ = 4096ull * 256;
    float* ws  = (float*)d_ws;
    float* Qs  = ws;            // Q_self   = A@Wq_aa + bq_aa
    float* Ks  = ws + 1 * MSZ;  // K_self   = A@Wk_aa + bk_aa
    float* Vp  = ws + 2 * MSZ;  // V        = A@Wv_a  + bv_a
    float* Qc  = ws + 3 * MSZ;  // Q_cross  = A@Wk_ab + bk_ab
    float* Kc  = ws + 4 * MSZ;  // K_cross  = B@Wq_bb + bq_bb
    float* ctx = ws + 5 * MSZ;  // attention output [4096,256]

    dim3 pgrid(20, 64);
    proj5_kernel<<<pgrid, 256, 0, stream>>>(A, B,
        Wq_aa, Wk_aa, Wv_a, Wk_ab, Wq_bb,
        bq_aa, bk_aa, bv_a, bk_ab, bq_bb,
        Qs, Ks, Vp, Qc, Kc);

    dim3 agrid(32, 8, 2);
    attn_mfma_kernel<<<agrid, 256, 0, stream>>>(Qs, Ks, Qc, Kc, Vp, ctx);

    dim3 ggrid(4, 64);
    gemm_bias_kernel<<<ggrid, 256, 0, stream>>>(ctx, Wo, bo, out, 4096, 256, 256);
}

// Round 3
// 153.044 us; speedup vs baseline: 4.8052x; 1.7162x over previous
//
#include <hip/hip_runtime.h>
#include <math.h>

#define SCALE 0.17677669529663687f  // 1/sqrt(32)

typedef __attribute__((ext_vector_type(8))) short bf16x8;
typedef __attribute__((ext_vector_type(4))) float f32x4;
typedef unsigned int u32;
typedef unsigned short u16;

#define MFMA16(a, b, c) __builtin_amdgcn_mfma_f32_16x16x32_bf16(a, b, c, 0, 0, 0)

__device__ inline u32 bf16rne(float x) {
    u32 u = __float_as_uint(x);
    return (u + 0x7FFFu + ((u >> 16) & 1u)) >> 16;
}
__device__ inline float bf16tof(u32 h) { return __uint_as_float(h << 16); }
// byte addr within a tile of 128-byte rows, XOR-swizzled (G4 / T2)
__device__ inline int swzb(int row, int b) { return row * 128 + (b ^ ((row & 7) << 4)); }

typedef __attribute__((address_space(1))) const u32 gu32;
typedef __attribute__((address_space(3))) u32 lu32;
#define GL16(g, l) __builtin_amdgcn_global_load_lds((gu32*)(const void*)(g), (lu32*)(void*)(l), 16, 0, 0)

// ---------------------------------------------------------------------------
// Convert A and B (fp32 [4096][768]) to split hi/lo bf16.
// grid (3072, 2), 256 thr; thread handles 4 elements.
// ---------------------------------------------------------------------------
__global__ __launch_bounds__(256) void conv_ab(
    const float* __restrict__ A, const float* __restrict__ B,
    u16* __restrict__ Ahi, u16* __restrict__ Alo,
    u16* __restrict__ Bhi, u16* __restrict__ Blo)
{
    const float* src = blockIdx.y ? B : A;
    u16* dh = blockIdx.y ? Bhi : Ahi;
    u16* dl = blockIdx.y ? Blo : Alo;
    size_t i = ((size_t)blockIdx.x * 256 + threadIdx.x) * 4;
    float4 f = *(const float4*)&src[i];
    u32 h0 = bf16rne(f.x), h1 = bf16rne(f.y), h2 = bf16rne(f.z), h3 = bf16rne(f.w);
    ushort4 hv = {(u16)h0, (u16)h1, (u16)h2, (u16)h3};
    ushort4 lv = {(u16)bf16rne(f.x - bf16tof(h0)), (u16)bf16rne(f.y - bf16tof(h1)),
                  (u16)bf16rne(f.z - bf16tof(h2)), (u16)bf16rne(f.w - bf16tof(h3))};
    *(ushort4*)&dh[i] = hv;
    *(ushort4*)&dl[i] = lv;
}

// ---------------------------------------------------------------------------
// Convert + transpose weights: g<5: W[768][256] -> Wt[g][256][768] hi/lo;
// g==5: Wo[256][256] -> Wot[256][256] hi/lo.  grid (12, 4, 6), 256 thr.
// ---------------------------------------------------------------------------
__global__ __launch_bounds__(256) void conv_w(
    const float* __restrict__ W0, const float* __restrict__ W1,
    const float* __restrict__ W2, const float* __restrict__ W3,
    const float* __restrict__ W4, const float* __restrict__ Wo,
    u16* __restrict__ W5t_hi, u16* __restrict__ W5t_lo,
    u16* __restrict__ Wot_hi, u16* __restrict__ Wot_lo)
{
    const int g = blockIdx.z;
    const float* W; int K; u16 *dh, *dl;
    switch (g) {
        case 0: W = W0; K = 768; dh = W5t_hi;              dl = W5t_lo;              break;
        case 1: W = W1; K = 768; dh = W5t_hi + 196608;     dl = W5t_lo + 196608;     break;
        case 2: W = W2; K = 768; dh = W5t_hi + 2 * 196608; dl = W5t_lo + 2 * 196608; break;
        case 3: W = W3; K = 768; dh = W5t_hi + 3 * 196608; dl = W5t_lo + 3 * 196608; break;
        case 4: W = W4; K = 768; dh = W5t_hi + 4 * 196608; dl = W5t_lo + 4 * 196608; break;
        default: W = Wo; K = 256; dh = Wot_hi; dl = Wot_lo; break;
    }
    const int k0 = blockIdx.x * 64, n0 = blockIdx.y * 64;
    if (k0 >= K) return;
    __shared__ float T[64][65];
    const int t = threadIdx.x;
    #pragma unroll
    for (int rep = 0; rep < 4; ++rep) {
        int kr = rep * 16 + (t >> 4);
        int nc = (t & 15) * 4;
        float4 f = *(const float4*)&W[(size_t)(k0 + kr) * 256 + n0 + nc];
        T[kr][nc] = f.x; T[kr][nc + 1] = f.y; T[kr][nc + 2] = f.z; T[kr][nc + 3] = f.w;
    }
    __syncthreads();
    #pragma unroll
    for (int rep = 0; rep < 4; ++rep) {
        int idx = rep * 256 + t;
        int n = idx >> 4, kq = (idx & 15) * 4;
        ushort4 hv, lv;
        float v0 = T[kq + 0][n], v1 = T[kq + 1][n], v2 = T[kq + 2][n], v3 = T[kq + 3][n];
        u32 h0 = bf16rne(v0), h1 = bf16rne(v1), h2 = bf16rne(v2), h3 = bf16rne(v3);
        hv = {(u16)h0, (u16)h1, (u16)h2, (u16)h3};
        lv = {(u16)bf16rne(v0 - bf16tof(h0)), (u16)bf16rne(v1 - bf16tof(h1)),
              (u16)bf16rne(v2 - bf16tof(h2)), (u16)bf16rne(v3 - bf16tof(h3))};
        size_t o = (size_t)(n0 + n) * K + k0 + kq;
        *(ushort4*)&dh[o] = hv;
        *(ushort4*)&dl[o] = lv;
    }
}

// ---------------------------------------------------------------------------
// 5-way projection, split-bf16 3-MFMA. grid (20, 64): bx>>2 = group,
// (bx&3)*64 = col tile, by*64 = row tile. 4 waves, wave = 16 rows x 64 cols.
// Outputs packed for attention:
//  g0: Q_self -> Qpk[row][h][d]      (SCALE folded)
//  g3: Q_cross-> Qpk[row][h][32+d]   (SCALE folded)
//  g1: K_self -> Kpk[row][h][d]
//  g4: K_cross-> Kpk[row][h][32+d]
//  g2: V      -> Vt[b][h][d][k]  (LDS-transposed epilogue)
// ---------------------------------------------------------------------------
__global__ __launch_bounds__(256, 2) void proj5_mfma(
    const u16* __restrict__ Ahi, const u16* __restrict__ Alo,
    const u16* __restrict__ Bhi, const u16* __restrict__ Blo,
    const u16* __restrict__ W5t_hi, const u16* __restrict__ W5t_lo,
    const float* __restrict__ b0, const float* __restrict__ b1,
    const float* __restrict__ b2, const float* __restrict__ b3,
    const float* __restrict__ b4,
    u16* __restrict__ Qpk_hi, u16* __restrict__ Qpk_lo,
    u16* __restrict__ Kpk_hi, u16* __restrict__ Kpk_lo,
    u16* __restrict__ Vt_hi,  u16* __restrict__ Vt_lo)
{
    __shared__ u16 XH[64 * 64], XL[64 * 64], WH[64 * 64], WL[64 * 64];

    const int t = threadIdx.x, w = t >> 6, l = t & 63;
    const int l15 = l & 15, lg = l >> 4;
    const int g  = blockIdx.x >> 2;
    const int bn = (blockIdx.x & 3) * 64;
    const int bm = blockIdx.y * 64;

    const u16* Xhi = (g == 4) ? Bhi : Ahi;
    const u16* Xlo = (g == 4) ? Blo : Alo;
    const u16* Wh  = W5t_hi + (size_t)g * 196608;
    const u16* Wl  = W5t_lo + (size_t)g * 196608;
    const float* bias;
    switch (g) {
        case 0: bias = b0; break;
        case 1: bias = b1; break;
        case 2: bias = b2; break;
        case 3: bias = b3; break;
        default: bias = b4; break;
    }

    // staging role per wave
    const u16* srole = (w == 0) ? Xhi : (w == 1) ? Xlo : (w == 2) ? Wh : Wl;
    u16* drole = (w == 0) ? XH : (w == 1) ? XL : (w == 2) ? WH : WL;
    const int rbase = (w < 2) ? bm : bn;

    f32x4 acc[4] = {{0.f,0.f,0.f,0.f},{0.f,0.f,0.f,0.f},{0.f,0.f,0.f,0.f},{0.f,0.f,0.f,0.f}};

    for (int k0 = 0; k0 < 768; k0 += 64) {
        __syncthreads();
        #pragma unroll
        for (int c = 0; c < 8; ++c) {
            int r = c * 8 + (l >> 3);
            int swz = ((l & 7) * 16) ^ ((r & 7) << 4);
            const u16* src = srole + (size_t)(rbase + r) * 768 + k0 + (swz >> 1);
            GL16(src, &drole[c * 8 * 64]);
        }
        __syncthreads();
        #pragma unroll
        for (int s = 0; s < 2; ++s) {
            int byo = s * 64 + lg * 16;
            bf16x8 ah = *(const bf16x8*)((const char*)XH + swzb(w * 16 + l15, byo));
            bf16x8 al = *(const bf16x8*)((const char*)XL + swzb(w * 16 + l15, byo));
            #pragma unroll
            for (int cj = 0; cj < 4; ++cj) {
                bf16x8 bh = *(const bf16x8*)((const char*)WH + swzb(cj * 16 + l15, byo));
                bf16x8 bl = *(const bf16x8*)((const char*)WL + swzb(cj * 16 + l15, byo));
                acc[cj] = MFMA16(ah, bh, acc[cj]);
                acc[cj] = MFMA16(al, bh, acc[cj]);
                acc[cj] = MFMA16(ah, bl, acc[cj]);
            }
        }
    }

    float biasv[4];
    #pragma unroll
    for (int cj = 0; cj < 4; ++cj) biasv[cj] = bias[bn + cj * 16 + l15];

    if (g != 2) {
        u16* Dh = (g == 0 || g == 3) ? Qpk_hi : Kpk_hi;
        u16* Dl = (g == 0 || g == 3) ? Qpk_lo : Kpk_lo;
        const int dofs = (g == 3 || g == 4) ? 32 : 0;
        const bool scl = (g == 0 || g == 3);
        #pragma unroll
        for (int cj = 0; cj < 4; ++cj) {
            int c = bn + cj * 16 + l15;
            int h = c >> 5, d = (c & 31) + dofs;
            #pragma unroll
            for (int r = 0; r < 4; ++r) {
                int row = bm + w * 16 + lg * 4 + r;
                float y = acc[cj][r] + biasv[cj];
                if (scl) y *= SCALE;
                u32 hb = bf16rne(y);
                size_t o = ((size_t)row * 8 + h) * 64 + d;
                Dh[o] = (u16)hb;
                Dl[o] = (u16)bf16rne(y - bf16tof(hb));
            }
        }
    } else {
        // LDS transpose: write [d][k] swizzled into XH/XL, then coalesced Vt store
        __syncthreads();
        #pragma unroll
        for (int cj = 0; cj < 4; ++cj) {
            int dl = cj * 16 + l15;
            #pragma unroll
            for (int r = 0; r < 4; ++r) {
                int kl = w * 16 + lg * 4 + r;
                float y = acc[cj][r] + biasv[cj];
                u32 hb = bf16rne(y);
                int byo = (2 * kl) ^ ((dl & 7) << 4);
                *(u16*)((char*)XH + dl * 128 + byo) = (u16)hb;
                *(u16*)((char*)XL + dl * 128 + byo) = (u16)bf16rne(y - bf16tof(hb));
            }
        }
        __syncthreads();
        const int b = bm >> 11, kb = bm & 2047;
        #pragma unroll
        for (int rep = 0; rep < 4; ++rep) {
            int idx = rep * 256 + t;
            int dl = idx >> 4, kq = idx & 15;
            int c = bn + dl;
            int h = c >> 5, d = c & 31;
            int byo = (8 * kq) ^ ((dl & 7) << 4);
            ushort4 hv = *(const ushort4*)((const char*)XH + dl * 128 + byo);
            ushort4 lv = *(const ushort4*)((const char*)XL + dl * 128 + byo);
            size_t o = (((size_t)b * 8 + h) * 32 + d) * 2048 + kb + kq * 4;
            *(ushort4*)&Vt_hi[o] = hv;
            *(ushort4*)&Vt_lo[o] = lv;
        }
    }
}

// ---------------------------------------------------------------------------
// MFMA flash attention, split-bf16, staging via global_load_lds from packed
// pre-converted buffers. grid (32, 8, 2), 4 waves, wave = 16 q rows.
// ---------------------------------------------------------------------------
__global__ __launch_bounds__(256, 2) void attn_mfma2(
    const u16* __restrict__ Qpk_hi, const u16* __restrict__ Qpk_lo,
    const u16* __restrict__ Kpk_hi, const u16* __restrict__ Kpk_lo,
    const u16* __restrict__ Vt_hi,  const u16* __restrict__ Vt_lo,
    u16* __restrict__ Cx_hi, u16* __restrict__ Cx_lo)
{
    __shared__ u16 KH[64 * 64], KL[64 * 64], VH[32 * 64], VL[32 * 64];
    __shared__ u16 PH[4][16 * 64], PL[4][16 * 64];

    const int t = threadIdx.x, w = t >> 6, l = t & 63;
    const int l15 = l & 15, lg = l >> 4;
    const int b = blockIdx.z, h = blockIdx.y;
    const int q0 = blockIdx.x * 64 + w * 16;
    const int base = b * 2048;
    const int hc = h * 32;

    // Q fragments (SCALE pre-folded)
    bf16x8 qh[2], ql[2];
    {
        size_t ro = ((size_t)(base + q0 + l15) * 8 + h) * 64;
        #pragma unroll
        for (int s = 0; s < 2; ++s) {
            qh[s] = *(const bf16x8*)&Qpk_hi[ro + s * 32 + lg * 8];
            ql[s] = *(const bf16x8*)&Qpk_lo[ro + s * 32 + lg * 8];
        }
    }

    float m_i[4] = {-INFINITY, -INFINITY, -INFINITY, -INFINITY};
    float l_i[4] = {0.f, 0.f, 0.f, 0.f};
    f32x4 o0 = {0.f, 0.f, 0.f, 0.f}, o1 = {0.f, 0.f, 0.f, 0.f};

    for (int k0 = 0; k0 < 2048; k0 += 64) {
        __syncthreads();
        // ---- stage K/V tiles: 24 x 1KB chunks, wave w takes c = w, w+4, ...
        #pragma unroll
        for (int i = 0; i < 6; ++i) {
            int c = w + i * 4;
            const u16* sb; u16* db; int r0;
            if (c < 8)       { sb = Kpk_hi; db = KH; r0 = c * 8; }
            else if (c < 16) { sb = Kpk_lo; db = KL; r0 = (c - 8) * 8; }
            else if (c < 20) { sb = Vt_hi;  db = VH; r0 = (c - 16) * 8; }
            else             { sb = Vt_lo;  db = VL; r0 = (c - 20) * 8; }
            int r = r0 + (l >> 3);
            int swz = ((l & 7) * 16) ^ ((r & 7) << 4);
            const u16* src;
            if (c < 16) src = sb + ((size_t)(base + k0 + r) * 8 + h) * 64 + (swz >> 1);
            else        src = sb + (((size_t)b * 8 + h) * 32 + r) * 2048 + k0 + (swz >> 1);
            GL16(src, &db[r0 * 64]);
        }
        __syncthreads();

        // ---- S = Q @ K^T (16q x 64k), split-bf16 3-MFMA ----
        f32x4 sa[4] = {{0.f,0.f,0.f,0.f},{0.f,0.f,0.f,0.f},{0.f,0.f,0.f,0.f},{0.f,0.f,0.f,0.f}};
        #pragma unroll
        for (int s = 0; s < 2; ++s) {
            int byo = s * 64 + lg * 16;
            #pragma unroll
            for (int cj = 0; cj < 4; ++cj) {
                bf16x8 kh = *(const bf16x8*)((const char*)KH + swzb(cj * 16 + l15, byo));
                bf16x8 kl = *(const bf16x8*)((const char*)KL + swzb(cj * 16 + l15, byo));
                sa[cj] = MFMA16(qh[s], kh, sa[cj]);
                sa[cj] = MFMA16(ql[s], kh, sa[cj]);
                sa[cj] = MFMA16(qh[s], kl, sa[cj]);
            }
        }

        // ---- online softmax across the 16-lane col group ----
        #pragma unroll
        for (int r = 0; r < 4; ++r) {
            float tmax = fmaxf(fmaxf(sa[0][r], sa[1][r]), fmaxf(sa[2][r], sa[3][r]));
            #pragma unroll
            for (int mk = 1; mk < 16; mk <<= 1)
                tmax = fmaxf(tmax, __shfl_xor(tmax, mk));
            float mnew = fmaxf(m_i[r], tmax);
            float scl = __expf(m_i[r] - mnew);
            m_i[r] = mnew;
            float tsum = 0.f;
            #pragma unroll
            for (int cj = 0; cj < 4; ++cj) {
                float pv = __expf(sa[cj][r] - mnew);
                sa[cj][r] = pv;
                tsum += pv;
            }
            #pragma unroll
            for (int mk = 1; mk < 16; mk <<= 1)
                tsum += __shfl_xor(tsum, mk);
            l_i[r] = l_i[r] * scl + tsum;
            o0[r] *= scl;
            o1[r] *= scl;
        }

        // ---- P -> split bf16 in per-wave LDS ----
        #pragma unroll
        for (int r = 0; r < 4; ++r) {
            #pragma unroll
            for (int cj = 0; cj < 4; ++cj) {
                float pv = sa[cj][r];
                u32 hb = bf16rne(pv);
                int byo = swzb(lg * 4 + r, 2 * (cj * 16 + l15));
                *(u16*)((char*)PH[w] + byo) = (u16)hb;
                *(u16*)((char*)PL[w] + byo) = (u16)bf16rne(pv - bf16tof(hb));
            }
        }

        // ---- O += P @ V (16q x 32d), split-bf16 3-MFMA ----
        #pragma unroll
        for (int ks = 0; ks < 2; ++ks) {
            int byo = ks * 64 + lg * 16;
            bf16x8 ph  = *(const bf16x8*)((const char*)PH[w] + swzb(l15, byo));
            bf16x8 pl  = *(const bf16x8*)((const char*)PL[w] + swzb(l15, byo));
            bf16x8 vh0 = *(const bf16x8*)((const char*)VH + swzb(l15, byo));
            bf16x8 vl0 = *(const bf16x8*)((const char*)VL + swzb(l15, byo));
            bf16x8 vh1 = *(const bf16x8*)((const char*)VH + swzb(16 + l15, byo));
            bf16x8 vl1 = *(const bf16x8*)((const char*)VL + swzb(16 + l15, byo));
            o0 = MFMA16(ph, vh0, o0);
            o0 = MFMA16(pl, vh0, o0);
            o0 = MFMA16(ph, vl0, o0);
            o1 = MFMA16(ph, vh1, o1);
            o1 = MFMA16(pl, vh1, o1);
            o1 = MFMA16(ph, vl1, o1);
        }
    }

    // ---- epilogue: normalize, split to hi/lo bf16 ctx ----
    #pragma unroll
    for (int r = 0; r < 4; ++r) {
        float inv = 1.0f / l_i[r];
        size_t orow = (size_t)(base + q0 + lg * 4 + r) * 256 + hc;
        float y0 = o0[r] * inv, y1 = o1[r] * inv;
        u32 h0 = bf16rne(y0), h1 = bf16rne(y1);
        Cx_hi[orow + l15] = (u16)h0;
        Cx_lo[orow + l15] = (u16)bf16rne(y0 - bf16tof(h0));
        Cx_hi[orow + 16 + l15] = (u16)h1;
        Cx_lo[orow + 16 + l15] = (u16)bf16rne(y1 - bf16tof(h1));
    }
}

// ---------------------------------------------------------------------------
// Final GEMM: out = ctx @ Wo + bo, split-bf16 3-MFMA. M=4096 K=256 N=256.
// grid (4, 64), 4 waves.
// ---------------------------------------------------------------------------
__global__ __launch_bounds__(256, 2) void gemm_out_mfma(
    const u16* __restrict__ Xhi, const u16* __restrict__ Xlo,
    const u16* __restrict__ Wth, const u16* __restrict__ Wtl,
    const float* __restrict__ bias, float* __restrict__ out)
{
    __shared__ u16 XH[64 * 64], XL[64 * 64], WH[64 * 64], WL[64 * 64];
    const int t = threadIdx.x, w = t >> 6, l = t & 63;
    const int l15 = l & 15, lg = l >> 4;
    const int bn = blockIdx.x * 64, bm = blockIdx.y * 64;

    const u16* srole = (w == 0) ? Xhi : (w == 1) ? Xlo : (w == 2) ? Wth : Wtl;
    u16* drole = (w == 0) ? XH : (w == 1) ? XL : (w == 2) ? WH : WL;
    const int rbase = (w < 2) ? bm : bn;

    f32x4 acc[4] = {{0.f,0.f,0.f,0.f},{0.f,0.f,0.f,0.f},{0.f,0.f,0.f,0.f},{0.f,0.f,0.f,0.f}};

    for (int k0 = 0; k0 < 256; k0 += 64) {
        __syncthreads();
        #pragma unroll
        for (int c = 0; c < 8; ++c) {
            int r = c * 8 + (l >> 3);
            int swz = ((l & 7) * 16) ^ ((r & 7) << 4);
            const u16* src = srole + (size_t)(rbase + r) * 256 + k0 + (swz >> 1);
            GL16(src, &drole[c * 8 * 64]);
        }
        __syncthreads();
        #pragma unroll
        for (int s = 0; s < 2; ++s) {
            int byo = s * 64 + lg * 16;
            bf16x8 ah = *(const bf16x8*)((const char*)XH + swzb(w * 16 + l15, byo));
            bf16x8 al = *(const bf16x8*)((const char*)XL + swzb(w * 16 + l15, byo));
            #pragma unroll
            for (int cj = 0; cj < 4; ++cj) {
                bf16x8 bh = *(const bf16x8*)((const char*)WH + swzb(cj * 16 + l15, byo));
                bf16x8 bl = *(const bf16x8*)((const char*)WL + swzb(cj * 16 + l15, byo));
                acc[cj] = MFMA16(ah, bh, acc[cj]);
                acc[cj] = MFMA16(al, bh, acc[cj]);
                acc[cj] = MFMA16(ah, bl, acc[cj]);
            }
        }
    }

    #pragma unroll
    for (int cj = 0; cj < 4; ++cj) {
        float bv = bias[bn + cj * 16 + l15];
        #pragma unroll
        for (int r = 0; r < 4; ++r) {
            int row = bm + w * 16 + lg * 4 + r;
            out[(size_t)row * 256 + bn + cj * 16 + l15] = acc[cj][r] + bv;
        }
    }
}

// ---------------------------------------------------------------------------
extern "C" void kernel_launch(void* const* d_in, const int* in_sizes, int n_in,
                              void* d_out, int out_size, void* d_ws, size_t ws_size,
                              hipStream_t stream) {
    const float* A     = (const float*)d_in[0];
    const float* B     = (const float*)d_in[1];
    const float* Wq_aa = (const float*)d_in[2];
    const float* bq_aa = (const float*)d_in[3];
    const float* Wk_aa = (const float*)d_in[4];
    const float* bk_aa = (const float*)d_in[5];
    const float* Wv_a  = (const float*)d_in[6];
    const float* bv_a  = (const float*)d_in[7];
    const float* Wk_ab = (const float*)d_in[8];
    const float* bk_ab = (const float*)d_in[9];
    const float* Wq_bb = (const float*)d_in[10];
    const float* bq_bb = (const float*)d_in[11];
    const float* Wo    = (const float*)d_in[12];
    const float* bo    = (const float*)d_in[13];
    float* out = (float*)d_out;

    char* p = (char*)d_ws;
    u16* Ahi = (u16*)p; p += 6291456;
    u16* Alo = (u16*)p; p += 6291456;
    u16* Bhi = (u16*)p; p += 6291456;
    u16* Blo = (u16*)p; p += 6291456;
    u16* W5t_hi = (u16*)p; p += 1966080;
    u16* W5t_lo = (u16*)p; p += 1966080;
    u16* Wot_hi = (u16*)p; p += 131072;
    u16* Wot_lo = (u16*)p; p += 131072;
    u16* Qpk_hi = (u16*)p; p += 4194304;
    u16* Qpk_lo = (u16*)p; p += 4194304;
    u16* Kpk_hi = (u16*)p; p += 4194304;
    u16* Kpk_lo = (u16*)p; p += 4194304;
    u16* Vt_hi  = (u16*)p; p += 2097152;
    u16* Vt_lo  = (u16*)p; p += 2097152;
    u16* Cx_hi  = (u16*)p; p += 2097152;
    u16* Cx_lo  = (u16*)p; p += 2097152;

    conv_ab<<<dim3(3072, 2), 256, 0, stream>>>(A, B, Ahi, Alo, Bhi, Blo);
    conv_w<<<dim3(12, 4, 6), 256, 0, stream>>>(Wq_aa, Wk_aa, Wv_a, Wk_ab, Wq_bb, Wo,
                                               W5t_hi, W5t_lo, Wot_hi, Wot_lo);
    proj5_mfma<<<dim3(20, 64), 256, 0, stream>>>(Ahi, Alo, Bhi, Blo, W5t_hi, W5t_lo,
                                                 bq_aa, bk_aa, bv_a, bk_ab, bq_bb,
                                                 Qpk_hi, Qpk_lo, Kpk_hi, Kpk_lo, Vt_hi, Vt_lo);
    attn_mfma2<<<dim3(32, 8, 2), 256, 0, stream>>>(Qpk_hi, Qpk_lo, Kpk_hi, Kpk_lo,
                                                   Vt_hi, Vt_lo, Cx_hi, Cx_lo);
    gemm_out_mfma<<<dim3(4, 64), 256, 0, stream>>>(Cx_hi, Cx_lo, Wot_hi, Wot_lo, bo, out);
}

// Round 4
// 148.123 us; speedup vs baseline: 4.9648x; 1.0332x over previous
//
#include <hip/hip_runtime.h>
#include <math.h>

#define SCALE 0.17677669529663687f  // 1/sqrt(32)

typedef __attribute__((ext_vector_type(8))) short bf16x8;
typedef __attribute__((ext_vector_type(4))) float f32x4;
typedef unsigned int u32;
typedef unsigned short u16;

#define MFMA16(a, b, c) __builtin_amdgcn_mfma_f32_16x16x32_bf16(a, b, c, 0, 0, 0)

__device__ inline u32 bf16rne(float x) {
    u32 u = __float_as_uint(x);
    return (u + 0x7FFFu + ((u >> 16) & 1u)) >> 16;
}
__device__ inline float bf16tof(u32 h) { return __uint_as_float(h << 16); }
// byte addr within a tile of 128-byte rows, XOR-swizzled (G4 / T2)
__device__ inline int swzb(int row, int b) { return row * 128 + (b ^ ((row & 7) << 4)); }

typedef __attribute__((address_space(1))) const u32 gu32;
typedef __attribute__((address_space(3))) u32 lu32;
#define GL16(g, l) __builtin_amdgcn_global_load_lds((gu32*)(const void*)(g), (lu32*)(void*)(l), 16, 0, 0)

// ---------------------------------------------------------------------------
// Convert A and B (fp32 [4096][768]) to split hi/lo bf16.
// ---------------------------------------------------------------------------
__global__ __launch_bounds__(256) void conv_ab(
    const float* __restrict__ A, const float* __restrict__ B,
    u16* __restrict__ Ahi, u16* __restrict__ Alo,
    u16* __restrict__ Bhi, u16* __restrict__ Blo)
{
    const float* src = blockIdx.y ? B : A;
    u16* dh = blockIdx.y ? Bhi : Ahi;
    u16* dl = blockIdx.y ? Blo : Alo;
    size_t i = ((size_t)blockIdx.x * 256 + threadIdx.x) * 4;
    float4 f = *(const float4*)&src[i];
    u32 h0 = bf16rne(f.x), h1 = bf16rne(f.y), h2 = bf16rne(f.z), h3 = bf16rne(f.w);
    ushort4 hv = {(u16)h0, (u16)h1, (u16)h2, (u16)h3};
    ushort4 lv = {(u16)bf16rne(f.x - bf16tof(h0)), (u16)bf16rne(f.y - bf16tof(h1)),
                  (u16)bf16rne(f.z - bf16tof(h2)), (u16)bf16rne(f.w - bf16tof(h3))};
    *(ushort4*)&dh[i] = hv;
    *(ushort4*)&dl[i] = lv;
}

// ---------------------------------------------------------------------------
// Convert + transpose weights: g<5: W[768][256] -> Wt[g][256][768] hi/lo;
// g==5: Wo[256][256] -> Wot[256][256] hi/lo.  grid (12, 4, 6), 256 thr.
// ---------------------------------------------------------------------------
__global__ __launch_bounds__(256) void conv_w(
    const float* __restrict__ W0, const float* __restrict__ W1,
    const float* __restrict__ W2, const float* __restrict__ W3,
    const float* __restrict__ W4, const float* __restrict__ Wo,
    u16* __restrict__ W5t_hi, u16* __restrict__ W5t_lo,
    u16* __restrict__ Wot_hi, u16* __restrict__ Wot_lo)
{
    const int g = blockIdx.z;
    const float* W; int K; u16 *dh, *dl;
    switch (g) {
        case 0: W = W0; K = 768; dh = W5t_hi;              dl = W5t_lo;              break;
        case 1: W = W1; K = 768; dh = W5t_hi + 196608;     dl = W5t_lo + 196608;     break;
        case 2: W = W2; K = 768; dh = W5t_hi + 2 * 196608; dl = W5t_lo + 2 * 196608; break;
        case 3: W = W3; K = 768; dh = W5t_hi + 3 * 196608; dl = W5t_lo + 3 * 196608; break;
        case 4: W = W4; K = 768; dh = W5t_hi + 4 * 196608; dl = W5t_lo + 4 * 196608; break;
        default: W = Wo; K = 256; dh = Wot_hi; dl = Wot_lo; break;
    }
    const int k0 = blockIdx.x * 64, n0 = blockIdx.y * 64;
    if (k0 >= K) return;
    __shared__ float T[64][65];
    const int t = threadIdx.x;
    #pragma unroll
    for (int rep = 0; rep < 4; ++rep) {
        int kr = rep * 16 + (t >> 4);
        int nc = (t & 15) * 4;
        float4 f = *(const float4*)&W[(size_t)(k0 + kr) * 256 + n0 + nc];
        T[kr][nc] = f.x; T[kr][nc + 1] = f.y; T[kr][nc + 2] = f.z; T[kr][nc + 3] = f.w;
    }
    __syncthreads();
    #pragma unroll
    for (int rep = 0; rep < 4; ++rep) {
        int idx = rep * 256 + t;
        int n = idx >> 4, kq = (idx & 15) * 4;
        ushort4 hv, lv;
        float v0 = T[kq + 0][n], v1 = T[kq + 1][n], v2 = T[kq + 2][n], v3 = T[kq + 3][n];
        u32 h0 = bf16rne(v0), h1 = bf16rne(v1), h2 = bf16rne(v2), h3 = bf16rne(v3);
        hv = {(u16)h0, (u16)h1, (u16)h2, (u16)h3};
        lv = {(u16)bf16rne(v0 - bf16tof(h0)), (u16)bf16rne(v1 - bf16tof(h1)),
              (u16)bf16rne(v2 - bf16tof(h2)), (u16)bf16rne(v3 - bf16tof(h3))};
        size_t o = (size_t)(n0 + n) * K + k0 + kq;
        *(ushort4*)&dh[o] = hv;
        *(ushort4*)&dl[o] = lv;
    }
}

// ---------------------------------------------------------------------------
// 5-way projection, split-bf16 3-MFMA. grid (20, 64).
//  g0: Q_self -> Qpk[row][h][d] (SCALE folded)   g3: Q_cross-> Qpk[..][32+d]
//  g1: K_self -> Kpk[row][h][d]                  g4: K_cross-> Kpk[..][32+d]
//  g2: V      -> Vt[b][h][d][k]  (LDS-transposed epilogue)
// ---------------------------------------------------------------------------
__global__ __launch_bounds__(256, 2) void proj5_mfma(
    const u16* __restrict__ Ahi, const u16* __restrict__ Alo,
    const u16* __restrict__ Bhi, const u16* __restrict__ Blo,
    const u16* __restrict__ W5t_hi, const u16* __restrict__ W5t_lo,
    const float* __restrict__ b0, const float* __restrict__ b1,
    const float* __restrict__ b2, const float* __restrict__ b3,
    const float* __restrict__ b4,
    u16* __restrict__ Qpk_hi, u16* __restrict__ Qpk_lo,
    u16* __restrict__ Kpk_hi, u16* __restrict__ Kpk_lo,
    u16* __restrict__ Vt_hi,  u16* __restrict__ Vt_lo)
{
    __shared__ u16 XH[64 * 64], XL[64 * 64], WH[64 * 64], WL[64 * 64];

    const int t = threadIdx.x, w = t >> 6, l = t & 63;
    const int l15 = l & 15, lg = l >> 4;
    const int g  = blockIdx.x >> 2;
    const int bn = (blockIdx.x & 3) * 64;
    const int bm = blockIdx.y * 64;

    const u16* Xhi = (g == 4) ? Bhi : Ahi;
    const u16* Xlo = (g == 4) ? Blo : Alo;
    const u16* Wh  = W5t_hi + (size_t)g * 196608;
    const u16* Wl  = W5t_lo + (size_t)g * 196608;
    const float* bias;
    switch (g) {
        case 0: bias = b0; break;
        case 1: bias = b1; break;
        case 2: bias = b2; break;
        case 3: bias = b3; break;
        default: bias = b4; break;
    }

    const u16* srole = (w == 0) ? Xhi : (w == 1) ? Xlo : (w == 2) ? Wh : Wl;
    u16* drole = (w == 0) ? XH : (w == 1) ? XL : (w == 2) ? WH : WL;
    const int rbase = (w < 2) ? bm : bn;

    f32x4 acc[4] = {{0.f,0.f,0.f,0.f},{0.f,0.f,0.f,0.f},{0.f,0.f,0.f,0.f},{0.f,0.f,0.f,0.f}};

    for (int k0 = 0; k0 < 768; k0 += 64) {
        __syncthreads();
        #pragma unroll
        for (int c = 0; c < 8; ++c) {
            int r = c * 8 + (l >> 3);
            int swz = ((l & 7) * 16) ^ ((r & 7) << 4);
            const u16* src = srole + (size_t)(rbase + r) * 768 + k0 + (swz >> 1);
            GL16(src, &drole[c * 8 * 64]);
        }
        __syncthreads();
        #pragma unroll
        for (int s = 0; s < 2; ++s) {
            int byo = s * 64 + lg * 16;
            bf16x8 ah = *(const bf16x8*)((const char*)XH + swzb(w * 16 + l15, byo));
            bf16x8 al = *(const bf16x8*)((const char*)XL + swzb(w * 16 + l15, byo));
            #pragma unroll
            for (int cj = 0; cj < 4; ++cj) {
                bf16x8 bh = *(const bf16x8*)((const char*)WH + swzb(cj * 16 + l15, byo));
                bf16x8 bl = *(const bf16x8*)((const char*)WL + swzb(cj * 16 + l15, byo));
                acc[cj] = MFMA16(ah, bh, acc[cj]);
                acc[cj] = MFMA16(al, bh, acc[cj]);
                acc[cj] = MFMA16(ah, bl, acc[cj]);
            }
        }
    }

    float biasv[4];
    #pragma unroll
    for (int cj = 0; cj < 4; ++cj) biasv[cj] = bias[bn + cj * 16 + l15];

    if (g != 2) {
        u16* Dh = (g == 0 || g == 3) ? Qpk_hi : Kpk_hi;
        u16* Dl = (g == 0 || g == 3) ? Qpk_lo : Kpk_lo;
        const int dofs = (g == 3 || g == 4) ? 32 : 0;
        const bool scl = (g == 0 || g == 3);
        #pragma unroll
        for (int cj = 0; cj < 4; ++cj) {
            int c = bn + cj * 16 + l15;
            int h = c >> 5, d = (c & 31) + dofs;
            #pragma unroll
            for (int r = 0; r < 4; ++r) {
                int row = bm + w * 16 + lg * 4 + r;
                float y = acc[cj][r] + biasv[cj];
                if (scl) y *= SCALE;
                u32 hb = bf16rne(y);
                size_t o = ((size_t)row * 8 + h) * 64 + d;
                Dh[o] = (u16)hb;
                Dl[o] = (u16)bf16rne(y - bf16tof(hb));
            }
        }
    } else {
        __syncthreads();
        #pragma unroll
        for (int cj = 0; cj < 4; ++cj) {
            int dl = cj * 16 + l15;
            #pragma unroll
            for (int r = 0; r < 4; ++r) {
                int kl = w * 16 + lg * 4 + r;
                float y = acc[cj][r] + biasv[cj];
                u32 hb = bf16rne(y);
                int byo = (2 * kl) ^ ((dl & 7) << 4);
                *(u16*)((char*)XH + dl * 128 + byo) = (u16)hb;
                *(u16*)((char*)XL + dl * 128 + byo) = (u16)bf16rne(y - bf16tof(hb));
            }
        }
        __syncthreads();
        const int b = bm >> 11, kb = bm & 2047;
        #pragma unroll
        for (int rep = 0; rep < 4; ++rep) {
            int idx = rep * 256 + t;
            int dl = idx >> 4, kq = idx & 15;
            int c = bn + dl;
            int h = c >> 5, d = c & 31;
            int byo = (8 * kq) ^ ((dl & 7) << 4);
            ushort4 hv = *(const ushort4*)((const char*)XH + dl * 128 + byo);
            ushort4 lv = *(const ushort4*)((const char*)XL + dl * 128 + byo);
            size_t o = (((size_t)b * 8 + h) * 32 + d) * 2048 + kb + kq * 4;
            *(ushort4*)&Vt_hi[o] = hv;
            *(ushort4*)&Vt_lo[o] = lv;
        }
    }
}

// ---------------------------------------------------------------------------
// MFMA flash attention, split-bf16, 4-way k-split for occupancy.
// grid (32, 8, 8): z = b*4+ks, block covers k in [ks*512, ks*512+512).
// Emits unnormalized partial O + (m,l) per q row in f32.
// ---------------------------------------------------------------------------
__global__ __launch_bounds__(256, 2) void attn_mfma3(
    const u16* __restrict__ Qpk_hi, const u16* __restrict__ Qpk_lo,
    const u16* __restrict__ Kpk_hi, const u16* __restrict__ Kpk_lo,
    const u16* __restrict__ Vt_hi,  const u16* __restrict__ Vt_lo,
    float* __restrict__ Opart, float* __restrict__ Oml)
{
    __shared__ u16 KH[64 * 64], KL[64 * 64], VH[32 * 64], VL[32 * 64];
    __shared__ u16 PH[4][16 * 64], PL[4][16 * 64];

    const int t = threadIdx.x, w = t >> 6, l = t & 63;
    const int l15 = l & 15, lg = l >> 4;
    const int z = blockIdx.z;
    const int b = z >> 2, ks = z & 3;
    const int h = blockIdx.y;
    const int q0 = blockIdx.x * 64 + w * 16;
    const int base = b * 2048;

    // Q fragments (SCALE pre-folded)
    bf16x8 qh[2], ql[2];
    {
        size_t ro = ((size_t)(base + q0 + l15) * 8 + h) * 64;
        #pragma unroll
        for (int s = 0; s < 2; ++s) {
            qh[s] = *(const bf16x8*)&Qpk_hi[ro + s * 32 + lg * 8];
            ql[s] = *(const bf16x8*)&Qpk_lo[ro + s * 32 + lg * 8];
        }
    }

    float m_i[4] = {-INFINITY, -INFINITY, -INFINITY, -INFINITY};
    float l_i[4] = {0.f, 0.f, 0.f, 0.f};
    f32x4 o0 = {0.f, 0.f, 0.f, 0.f}, o1 = {0.f, 0.f, 0.f, 0.f};

    const int kend = ks * 512 + 512;
    for (int k0 = ks * 512; k0 < kend; k0 += 64) {
        __syncthreads();
        // ---- stage K/V tiles: 24 x 1KB chunks, wave w takes c = w, w+4, ...
        #pragma unroll
        for (int i = 0; i < 6; ++i) {
            int c = w + i * 4;
            const u16* sb; u16* db; int r0;
            if (c < 8)       { sb = Kpk_hi; db = KH; r0 = c * 8; }
            else if (c < 16) { sb = Kpk_lo; db = KL; r0 = (c - 8) * 8; }
            else if (c < 20) { sb = Vt_hi;  db = VH; r0 = (c - 16) * 8; }
            else             { sb = Vt_lo;  db = VL; r0 = (c - 20) * 8; }
            int r = r0 + (l >> 3);
            int swz = ((l & 7) * 16) ^ ((r & 7) << 4);
            const u16* src;
            if (c < 16) src = sb + ((size_t)(base + k0 + r) * 8 + h) * 64 + (swz >> 1);
            else        src = sb + (((size_t)b * 8 + h) * 32 + r) * 2048 + k0 + (swz >> 1);
            GL16(src, &db[r0 * 64]);
        }
        __syncthreads();

        // ---- S = Q @ K^T (16q x 64k), split-bf16 3-MFMA ----
        f32x4 sa[4] = {{0.f,0.f,0.f,0.f},{0.f,0.f,0.f,0.f},{0.f,0.f,0.f,0.f},{0.f,0.f,0.f,0.f}};
        #pragma unroll
        for (int s = 0; s < 2; ++s) {
            int byo = s * 64 + lg * 16;
            #pragma unroll
            for (int cj = 0; cj < 4; ++cj) {
                bf16x8 kh = *(const bf16x8*)((const char*)KH + swzb(cj * 16 + l15, byo));
                bf16x8 kl = *(const bf16x8*)((const char*)KL + swzb(cj * 16 + l15, byo));
                sa[cj] = MFMA16(qh[s], kh, sa[cj]);
                sa[cj] = MFMA16(ql[s], kh, sa[cj]);
                sa[cj] = MFMA16(qh[s], kl, sa[cj]);
            }
        }

        // ---- online softmax across the 16-lane col group ----
        #pragma unroll
        for (int r = 0; r < 4; ++r) {
            float tmax = fmaxf(fmaxf(sa[0][r], sa[1][r]), fmaxf(sa[2][r], sa[3][r]));
            #pragma unroll
            for (int mk = 1; mk < 16; mk <<= 1)
                tmax = fmaxf(tmax, __shfl_xor(tmax, mk));
            float mnew = fmaxf(m_i[r], tmax);
            float scl = __expf(m_i[r] - mnew);
            m_i[r] = mnew;
            float tsum = 0.f;
            #pragma unroll
            for (int cj = 0; cj < 4; ++cj) {
                float pv = __expf(sa[cj][r] - mnew);
                sa[cj][r] = pv;
                tsum += pv;
            }
            #pragma unroll
            for (int mk = 1; mk < 16; mk <<= 1)
                tsum += __shfl_xor(tsum, mk);
            l_i[r] = l_i[r] * scl + tsum;
            o0[r] *= scl;
            o1[r] *= scl;
        }

        // ---- P -> split bf16 in per-wave LDS ----
        #pragma unroll
        for (int r = 0; r < 4; ++r) {
            #pragma unroll
            for (int cj = 0; cj < 4; ++cj) {
                float pv = sa[cj][r];
                u32 hb = bf16rne(pv);
                int byo = swzb(lg * 4 + r, 2 * (cj * 16 + l15));
                *(u16*)((char*)PH[w] + byo) = (u16)hb;
                *(u16*)((char*)PL[w] + byo) = (u16)bf16rne(pv - bf16tof(hb));
            }
        }

        // ---- O += P @ V (16q x 32d), split-bf16 3-MFMA ----
        #pragma unroll
        for (int kq = 0; kq < 2; ++kq) {
            int byo = kq * 64 + lg * 16;
            bf16x8 ph  = *(const bf16x8*)((const char*)PH[w] + swzb(l15, byo));
            bf16x8 pl  = *(const bf16x8*)((const char*)PL[w] + swzb(l15, byo));
            bf16x8 vh0 = *(const bf16x8*)((const char*)VH + swzb(l15, byo));
            bf16x8 vl0 = *(const bf16x8*)((const char*)VL + swzb(l15, byo));
            bf16x8 vh1 = *(const bf16x8*)((const char*)VH + swzb(16 + l15, byo));
            bf16x8 vl1 = *(const bf16x8*)((const char*)VL + swzb(16 + l15, byo));
            o0 = MFMA16(ph, vh0, o0);
            o0 = MFMA16(pl, vh0, o0);
            o0 = MFMA16(ph, vl0, o0);
            o1 = MFMA16(ph, vh1, o1);
            o1 = MFMA16(pl, vh1, o1);
            o1 = MFMA16(ph, vl1, o1);
        }
    }

    // ---- epilogue: write unnormalized partial O + (m,l) ----
    const int pb = (b * 8 + h) * 4 + ks;
    #pragma unroll
    for (int r = 0; r < 4; ++r) {
        int row = q0 + lg * 4 + r;
        size_t ob = ((size_t)pb * 2048 + row) * 32;
        Opart[ob + l15]      = o0[r];
        Opart[ob + 16 + l15] = o1[r];
        if (l15 == 0) {
            size_t mb = ((size_t)pb * 2048 + row) * 2;
            Oml[mb]     = m_i[r];
            Oml[mb + 1] = l_i[r];
        }
    }
}

// ---------------------------------------------------------------------------
// Merge 4 k-split partials -> normalized ctx (split bf16).
// grid (64, 8, 2), 256 thr; thread = (row-group, d), 4 row reps.
// ---------------------------------------------------------------------------
__global__ __launch_bounds__(256) void attn_merge(
    const float* __restrict__ Opart, const float* __restrict__ Oml,
    u16* __restrict__ Cx_hi, u16* __restrict__ Cx_lo)
{
    const int t = threadIdx.x;
    const int d = t & 31, rg = t >> 5;
    const int h = blockIdx.y, b = blockIdx.z;
    const int pb = (b * 8 + h) * 4;
    #pragma unroll
    for (int rr = 0; rr < 4; ++rr) {
        int row = blockIdx.x * 32 + rr * 8 + rg;
        float m[4], lv[4];
        #pragma unroll
        for (int i = 0; i < 4; ++i) {
            size_t mb = ((size_t)(pb + i) * 2048 + row) * 2;
            m[i]  = Oml[mb];
            lv[i] = Oml[mb + 1];
        }
        float M = fmaxf(fmaxf(m[0], m[1]), fmaxf(m[2], m[3]));
        float wgt[4], L = 0.f;
        #pragma unroll
        for (int i = 0; i < 4; ++i) { wgt[i] = __expf(m[i] - M); L += lv[i] * wgt[i]; }
        float o = 0.f;
        #pragma unroll
        for (int i = 0; i < 4; ++i)
            o += wgt[i] * Opart[((size_t)(pb + i) * 2048 + row) * 32 + d];
        float y = o / L;
        u32 hb = bf16rne(y);
        size_t orow = (size_t)(b * 2048 + row) * 256 + h * 32 + d;
        Cx_hi[orow] = (u16)hb;
        Cx_lo[orow] = (u16)bf16rne(y - bf16tof(hb));
    }
}

// ---------------------------------------------------------------------------
// Final GEMM: out = ctx @ Wo + bo, split-bf16 3-MFMA. grid (4, 64).
// ---------------------------------------------------------------------------
__global__ __launch_bounds__(256, 2) void gemm_out_mfma(
    const u16* __restrict__ Xhi, const u16* __restrict__ Xlo,
    const u16* __restrict__ Wth, const u16* __restrict__ Wtl,
    const float* __restrict__ bias, float* __restrict__ out)
{
    __shared__ u16 XH[64 * 64], XL[64 * 64], WH[64 * 64], WL[64 * 64];
    const int t = threadIdx.x, w = t >> 6, l = t & 63;
    const int l15 = l & 15, lg = l >> 4;
    const int bn = blockIdx.x * 64, bm = blockIdx.y * 64;

    const u16* srole = (w == 0) ? Xhi : (w == 1) ? Xlo : (w == 2) ? Wth : Wtl;
    u16* drole = (w == 0) ? XH : (w == 1) ? XL : (w == 2) ? WH : WL;
    const int rbase = (w < 2) ? bm : bn;

    f32x4 acc[4] = {{0.f,0.f,0.f,0.f},{0.f,0.f,0.f,0.f},{0.f,0.f,0.f,0.f},{0.f,0.f,0.f,0.f}};

    for (int k0 = 0; k0 < 256; k0 += 64) {
        __syncthreads();
        #pragma unroll
        for (int c = 0; c < 8; ++c) {
            int r = c * 8 + (l >> 3);
            int swz = ((l & 7) * 16) ^ ((r & 7) << 4);
            const u16* src = srole + (size_t)(rbase + r) * 256 + k0 + (swz >> 1);
            GL16(src, &drole[c * 8 * 64]);
        }
        __syncthreads();
        #pragma unroll
        for (int s = 0; s < 2; ++s) {
            int byo = s * 64 + lg * 16;
            bf16x8 ah = *(const bf16x8*)((const char*)XH + swzb(w * 16 + l15, byo));
            bf16x8 al = *(const bf16x8*)((const char*)XL + swzb(w * 16 + l15, byo));
            #pragma unroll
            for (int cj = 0; cj < 4; ++cj) {
                bf16x8 bh = *(const bf16x8*)((const char*)WH + swzb(cj * 16 + l15, byo));
                bf16x8 bl = *(const bf16x8*)((const char*)WL + swzb(cj * 16 + l15, byo));
                acc[cj] = MFMA16(ah, bh, acc[cj]);
                acc[cj] = MFMA16(al, bh, acc[cj]);
                acc[cj] = MFMA16(ah, bl, acc[cj]);
            }
        }
    }

    #pragma unroll
    for (int cj = 0; cj < 4; ++cj) {
        float bv = bias[bn + cj * 16 + l15];
        #pragma unroll
        for (int r = 0; r < 4; ++r) {
            int row = bm + w * 16 + lg * 4 + r;
            out[(size_t)row * 256 + bn + cj * 16 + l15] = acc[cj][r] + bv;
        }
    }
}

// ---------------------------------------------------------------------------
extern "C" void kernel_launch(void* const* d_in, const int* in_sizes, int n_in,
                              void* d_out, int out_size, void* d_ws, size_t ws_size,
                              hipStream_t stream) {
    const float* A     = (const float*)d_in[0];
    const float* B     = (const float*)d_in[1];
    const float* Wq_aa = (const float*)d_in[2];
    const float* bq_aa = (const float*)d_in[3];
    const float* Wk_aa = (const float*)d_in[4];
    const float* bk_aa = (const float*)d_in[5];
    const float* Wv_a  = (const float*)d_in[6];
    const float* bv_a  = (const float*)d_in[7];
    const float* Wk_ab = (const float*)d_in[8];
    const float* bk_ab = (const float*)d_in[9];
    const float* Wq_bb = (const float*)d_in[10];
    const float* bq_bb = (const float*)d_in[11];
    const float* Wo    = (const float*)d_in[12];
    const float* bo    = (const float*)d_in[13];
    float* out = (float*)d_out;

    char* p = (char*)d_ws;
    u16* Ahi = (u16*)p; p += 6291456;
    u16* Alo = (u16*)p; p += 6291456;
    u16* Bhi = (u16*)p; p += 6291456;
    u16* Blo = (u16*)p; p += 6291456;
    u16* W5t_hi = (u16*)p; p += 1966080;
    u16* W5t_lo = (u16*)p; p += 1966080;
    u16* Wot_hi = (u16*)p; p += 131072;
    u16* Wot_lo = (u16*)p; p += 131072;
    u16* Qpk_hi = (u16*)p; p += 4194304;
    u16* Qpk_lo = (u16*)p; p += 4194304;
    u16* Kpk_hi = (u16*)p; p += 4194304;
    u16* Kpk_lo = (u16*)p; p += 4194304;
    u16* Vt_hi  = (u16*)p; p += 2097152;
    u16* Vt_lo  = (u16*)p; p += 2097152;
    u16* Cx_hi  = (u16*)p; p += 2097152;
    u16* Cx_lo  = (u16*)p; p += 2097152;

    // k-split partials alias the A/B conversion buffers (dead after proj5):
    // Opart 64*2048*32*4 = 16.78 MB, Oml 64*2048*2*4 = 1.05 MB  (< 25.1 MB region)
    float* Opart = (float*)d_ws;
    float* Oml   = (float*)((char*)d_ws + 16777216);

    conv_ab<<<dim3(3072, 2), 256, 0, stream>>>(A, B, Ahi, Alo, Bhi, Blo);
    conv_w<<<dim3(12, 4, 6), 256, 0, stream>>>(Wq_aa, Wk_aa, Wv_a, Wk_ab, Wq_bb, Wo,
                                               W5t_hi, W5t_lo, Wot_hi, Wot_lo);
    proj5_mfma<<<dim3(20, 64), 256, 0, stream>>>(Ahi, Alo, Bhi, Blo, W5t_hi, W5t_lo,
                                                 bq_aa, bk_aa, bv_a, bk_ab, bq_bb,
                                                 Qpk_hi, Qpk_lo, Kpk_hi, Kpk_lo, Vt_hi, Vt_lo);
    attn_mfma3<<<dim3(32, 8, 8), 256, 0, stream>>>(Qpk_hi, Qpk_lo, Kpk_hi, Kpk_lo,
                                                   Vt_hi, Vt_lo, Opart, Oml);
    attn_merge<<<dim3(64, 8, 2), 256, 0, stream>>>(Opart, Oml, Cx_hi, Cx_lo);
    gemm_out_mfma<<<dim3(4, 64), 256, 0, stream>>>(Cx_hi, Cx_lo, Wot_hi, Wot_lo, bo, out);
}

// Round 5
// 125.672 us; speedup vs baseline: 5.8518x; 1.1786x over previous
//
#include <hip/hip_runtime.h>
#include <hip/hip_bf16.h>
#include <math.h>

#define SCALE 0.17677669529663687f  // 1/sqrt(32)

typedef __attribute__((ext_vector_type(8))) short bf16x8;
typedef __attribute__((ext_vector_type(4))) float f32x4;
typedef unsigned int u32;
typedef unsigned short u16;

#define MFMA16(a, b, c) __builtin_amdgcn_mfma_f32_16x16x32_bf16(a, b, c, 0, 0, 0)

__device__ inline u32 bf16rne(float x) {
    u32 u = __float_as_uint(x);
    return (u + 0x7FFFu + ((u >> 16) & 1u)) >> 16;
}
__device__ inline float bf16tof(u32 h) { return __uint_as_float(h << 16); }
// pack 2 floats -> 2 bf16 (RNE) in one u32 (lo = a); compiler emits v_cvt_pk_bf16_f32
__device__ inline u32 pkbf2(float a, float b) {
    union { __hip_bfloat162 h; u32 u; } cv;
    cv.h = __float22bfloat162_rn(make_float2(a, b));
    return cv.u;
}
// byte addr within a tile of 128-byte rows, XOR-swizzled (G4 / T2)
__device__ inline int swzb(int row, int b) { return row * 128 + (b ^ ((row & 7) << 4)); }

typedef __attribute__((address_space(1))) const u32 gu32;
typedef __attribute__((address_space(3))) u32 lu32;
#define GL16(g, l) __builtin_amdgcn_global_load_lds((gu32*)(const void*)(g), (lu32*)(void*)(l), 16, 0, 0)

// ---------------------------------------------------------------------------
// Convert A and B (fp32 [4096][768]) to split hi/lo bf16.
// ---------------------------------------------------------------------------
__global__ __launch_bounds__(256) void conv_ab(
    const float* __restrict__ A, const float* __restrict__ B,
    u16* __restrict__ Ahi, u16* __restrict__ Alo,
    u16* __restrict__ Bhi, u16* __restrict__ Blo)
{
    const float* src = blockIdx.y ? B : A;
    u16* dh = blockIdx.y ? Bhi : Ahi;
    u16* dl = blockIdx.y ? Blo : Alo;
    size_t i = ((size_t)blockIdx.x * 256 + threadIdx.x) * 4;
    float4 f = *(const float4*)&src[i];
    u32 h0 = bf16rne(f.x), h1 = bf16rne(f.y), h2 = bf16rne(f.z), h3 = bf16rne(f.w);
    ushort4 hv = {(u16)h0, (u16)h1, (u16)h2, (u16)h3};
    ushort4 lv = {(u16)bf16rne(f.x - bf16tof(h0)), (u16)bf16rne(f.y - bf16tof(h1)),
                  (u16)bf16rne(f.z - bf16tof(h2)), (u16)bf16rne(f.w - bf16tof(h3))};
    *(ushort4*)&dh[i] = hv;
    *(ushort4*)&dl[i] = lv;
}

// ---------------------------------------------------------------------------
// Convert + transpose weights: g<5: W[768][256] -> Wt[g][256][768] hi/lo;
// g==5: Wo[256][256] -> Wot[256][256] hi/lo.  grid (12, 4, 6), 256 thr.
// ---------------------------------------------------------------------------
__global__ __launch_bounds__(256) void conv_w(
    const float* __restrict__ W0, const float* __restrict__ W1,
    const float* __restrict__ W2, const float* __restrict__ W3,
    const float* __restrict__ W4, const float* __restrict__ Wo,
    u16* __restrict__ W5t_hi, u16* __restrict__ W5t_lo,
    u16* __restrict__ Wot_hi, u16* __restrict__ Wot_lo)
{
    const int g = blockIdx.z;
    const float* W; int K; u16 *dh, *dl;
    switch (g) {
        case 0: W = W0; K = 768; dh = W5t_hi;              dl = W5t_lo;              break;
        case 1: W = W1; K = 768; dh = W5t_hi + 196608;     dl = W5t_lo + 196608;     break;
        case 2: W = W2; K = 768; dh = W5t_hi + 2 * 196608; dl = W5t_lo + 2 * 196608; break;
        case 3: W = W3; K = 768; dh = W5t_hi + 3 * 196608; dl = W5t_lo + 3 * 196608; break;
        case 4: W = W4; K = 768; dh = W5t_hi + 4 * 196608; dl = W5t_lo + 4 * 196608; break;
        default: W = Wo; K = 256; dh = Wot_hi; dl = Wot_lo; break;
    }
    const int k0 = blockIdx.x * 64, n0 = blockIdx.y * 64;
    if (k0 >= K) return;
    __shared__ float T[64][65];
    const int t = threadIdx.x;
    #pragma unroll
    for (int rep = 0; rep < 4; ++rep) {
        int kr = rep * 16 + (t >> 4);
        int nc = (t & 15) * 4;
        float4 f = *(const float4*)&W[(size_t)(k0 + kr) * 256 + n0 + nc];
        T[kr][nc] = f.x; T[kr][nc + 1] = f.y; T[kr][nc + 2] = f.z; T[kr][nc + 3] = f.w;
    }
    __syncthreads();
    #pragma unroll
    for (int rep = 0; rep < 4; ++rep) {
        int idx = rep * 256 + t;
        int n = idx >> 4, kq = (idx & 15) * 4;
        ushort4 hv, lv;
        float v0 = T[kq + 0][n], v1 = T[kq + 1][n], v2 = T[kq + 2][n], v3 = T[kq + 3][n];
        u32 h0 = bf16rne(v0), h1 = bf16rne(v1), h2 = bf16rne(v2), h3 = bf16rne(v3);
        hv = {(u16)h0, (u16)h1, (u16)h2, (u16)h3};
        lv = {(u16)bf16rne(v0 - bf16tof(h0)), (u16)bf16rne(v1 - bf16tof(h1)),
              (u16)bf16rne(v2 - bf16tof(h2)), (u16)bf16rne(v3 - bf16tof(h3))};
        size_t o = (size_t)(n0 + n) * K + k0 + kq;
        *(ushort4*)&dh[o] = hv;
        *(ushort4*)&dl[o] = lv;
    }
}

// ---------------------------------------------------------------------------
// 5-way projection, split-bf16 3-MFMA. grid (20, 64).
//  g0: Q_self -> Qpk[row][h][d] (SCALE folded)   g3: Q_cross-> Qpk[..][32+d]
//  g1: K_self -> Kpk[row][h][d]                  g4: K_cross-> Kpk[..][32+d]
//  g2: V      -> Vt[b][h][d][k]  (LDS-transposed epilogue)
// ---------------------------------------------------------------------------
__global__ __launch_bounds__(256, 2) void proj5_mfma(
    const u16* __restrict__ Ahi, const u16* __restrict__ Alo,
    const u16* __restrict__ Bhi, const u16* __restrict__ Blo,
    const u16* __restrict__ W5t_hi, const u16* __restrict__ W5t_lo,
    const float* __restrict__ b0, const float* __restrict__ b1,
    const float* __restrict__ b2, const float* __restrict__ b3,
    const float* __restrict__ b4,
    u16* __restrict__ Qpk_hi, u16* __restrict__ Qpk_lo,
    u16* __restrict__ Kpk_hi, u16* __restrict__ Kpk_lo,
    u16* __restrict__ Vt_hi,  u16* __restrict__ Vt_lo)
{
    __shared__ u16 XH[64 * 64], XL[64 * 64], WH[64 * 64], WL[64 * 64];

    const int t = threadIdx.x, w = t >> 6, l = t & 63;
    const int l15 = l & 15, lg = l >> 4;
    const int g  = blockIdx.x >> 2;
    const int bn = (blockIdx.x & 3) * 64;
    const int bm = blockIdx.y * 64;

    const u16* Xhi = (g == 4) ? Bhi : Ahi;
    const u16* Xlo = (g == 4) ? Blo : Alo;
    const u16* Wh  = W5t_hi + (size_t)g * 196608;
    const u16* Wl  = W5t_lo + (size_t)g * 196608;
    const float* bias;
    switch (g) {
        case 0: bias = b0; break;
        case 1: bias = b1; break;
        case 2: bias = b2; break;
        case 3: bias = b3; break;
        default: bias = b4; break;
    }

    const u16* srole = (w == 0) ? Xhi : (w == 1) ? Xlo : (w == 2) ? Wh : Wl;
    u16* drole = (w == 0) ? XH : (w == 1) ? XL : (w == 2) ? WH : WL;
    const int rbase = (w < 2) ? bm : bn;

    f32x4 acc[4] = {{0.f,0.f,0.f,0.f},{0.f,0.f,0.f,0.f},{0.f,0.f,0.f,0.f},{0.f,0.f,0.f,0.f}};

    for (int k0 = 0; k0 < 768; k0 += 64) {
        __syncthreads();
        #pragma unroll
        for (int c = 0; c < 8; ++c) {
            int r = c * 8 + (l >> 3);
            int swz = ((l & 7) * 16) ^ ((r & 7) << 4);
            const u16* src = srole + (size_t)(rbase + r) * 768 + k0 + (swz >> 1);
            GL16(src, &drole[c * 8 * 64]);
        }
        __syncthreads();
        #pragma unroll
        for (int s = 0; s < 2; ++s) {
            int byo = s * 64 + lg * 16;
            bf16x8 ah = *(const bf16x8*)((const char*)XH + swzb(w * 16 + l15, byo));
            bf16x8 al = *(const bf16x8*)((const char*)XL + swzb(w * 16 + l15, byo));
            #pragma unroll
            for (int cj = 0; cj < 4; ++cj) {
                bf16x8 bh = *(const bf16x8*)((const char*)WH + swzb(cj * 16 + l15, byo));
                bf16x8 bl = *(const bf16x8*)((const char*)WL + swzb(cj * 16 + l15, byo));
                acc[cj] = MFMA16(ah, bh, acc[cj]);
                acc[cj] = MFMA16(al, bh, acc[cj]);
                acc[cj] = MFMA16(ah, bl, acc[cj]);
            }
        }
    }

    float biasv[4];
    #pragma unroll
    for (int cj = 0; cj < 4; ++cj) biasv[cj] = bias[bn + cj * 16 + l15];

    if (g != 2) {
        u16* Dh = (g == 0 || g == 3) ? Qpk_hi : Kpk_hi;
        u16* Dl = (g == 0 || g == 3) ? Qpk_lo : Kpk_lo;
        const int dofs = (g == 3 || g == 4) ? 32 : 0;
        const bool scl = (g == 0 || g == 3);
        #pragma unroll
        for (int cj = 0; cj < 4; ++cj) {
            int c = bn + cj * 16 + l15;
            int h = c >> 5, d = (c & 31) + dofs;
            #pragma unroll
            for (int r = 0; r < 4; ++r) {
                int row = bm + w * 16 + lg * 4 + r;
                float y = acc[cj][r] + biasv[cj];
                if (scl) y *= SCALE;
                u32 hb = bf16rne(y);
                size_t o = ((size_t)row * 8 + h) * 64 + d;
                Dh[o] = (u16)hb;
                Dl[o] = (u16)bf16rne(y - bf16tof(hb));
            }
        }
    } else {
        __syncthreads();
        #pragma unroll
        for (int cj = 0; cj < 4; ++cj) {
            int dl = cj * 16 + l15;
            #pragma unroll
            for (int r = 0; r < 4; ++r) {
                int kl = w * 16 + lg * 4 + r;
                float y = acc[cj][r] + biasv[cj];
                u32 hb = bf16rne(y);
                int byo = (2 * kl) ^ ((dl & 7) << 4);
                *(u16*)((char*)XH + dl * 128 + byo) = (u16)hb;
                *(u16*)((char*)XL + dl * 128 + byo) = (u16)bf16rne(y - bf16tof(hb));
            }
        }
        __syncthreads();
        const int b = bm >> 11, kb = bm & 2047;
        #pragma unroll
        for (int rep = 0; rep < 4; ++rep) {
            int idx = rep * 256 + t;
            int dl = idx >> 4, kq = idx & 15;
            int c = bn + dl;
            int h = c >> 5, d = c & 31;
            int byo = (8 * kq) ^ ((dl & 7) << 4);
            ushort4 hv = *(const ushort4*)((const char*)XH + dl * 128 + byo);
            ushort4 lv = *(const ushort4*)((const char*)XL + dl * 128 + byo);
            size_t o = (((size_t)b * 8 + h) * 32 + d) * 2048 + kb + kq * 4;
            *(ushort4*)&Vt_hi[o] = hv;
            *(ushort4*)&Vt_lo[o] = lv;
        }
    }
}

// ---------------------------------------------------------------------------
// MFMA flash attention v4: swapped QK^T (lane-local softmax), P hi-only,
// 4-way k-split. grid (32, 8, 8): z = b*4+ks. LDS = 32 KB -> 5 blocks/CU.
// S^T = mfma(K_frag, Q_frag): lane owns q = l&15, 16 k-values per tile.
// ---------------------------------------------------------------------------
__global__ __launch_bounds__(256, 5) void attn_mfma4(
    const u16* __restrict__ Qpk_hi, const u16* __restrict__ Qpk_lo,
    const u16* __restrict__ Kpk_hi, const u16* __restrict__ Kpk_lo,
    const u16* __restrict__ Vt_hi,  const u16* __restrict__ Vt_lo,
    float* __restrict__ Opart, float* __restrict__ Oml)
{
    __shared__ u16 KH[64 * 64], KL[64 * 64], VH[32 * 64], VL[32 * 64];
    __shared__ u16 PH[4][16 * 64];

    const int t = threadIdx.x, w = t >> 6, l = t & 63;
    const int l15 = l & 15, lg = l >> 4;
    const int z = blockIdx.z;
    const int b = z >> 2, ks = z & 3;
    const int h = blockIdx.y;
    const int q0 = blockIdx.x * 64 + w * 16;
    const int base = b * 2048;

    // Q fragments (SCALE pre-folded)
    bf16x8 qh[2], ql[2];
    {
        size_t ro = ((size_t)(base + q0 + l15) * 8 + h) * 64;
        #pragma unroll
        for (int s = 0; s < 2; ++s) {
            qh[s] = *(const bf16x8*)&Qpk_hi[ro + s * 32 + lg * 8];
            ql[s] = *(const bf16x8*)&Qpk_lo[ro + s * 32 + lg * 8];
        }
    }

    float m_i = -INFINITY, l_i = 0.f;   // per-lane scalars, q = l15 (x4 replicas)
    f32x4 o0 = {0.f, 0.f, 0.f, 0.f}, o1 = {0.f, 0.f, 0.f, 0.f};

    const int kend = ks * 512 + 512;
    for (int k0 = ks * 512; k0 < kend; k0 += 64) {
        __syncthreads();
        // ---- stage K/V tiles: 24 x 1KB chunks, wave w takes c = w, w+4, ...
        #pragma unroll
        for (int i = 0; i < 6; ++i) {
            int c = w + i * 4;
            const u16* sb; u16* db; int r0;
            if (c < 8)       { sb = Kpk_hi; db = KH; r0 = c * 8; }
            else if (c < 16) { sb = Kpk_lo; db = KL; r0 = (c - 8) * 8; }
            else if (c < 20) { sb = Vt_hi;  db = VH; r0 = (c - 16) * 8; }
            else             { sb = Vt_lo;  db = VL; r0 = (c - 20) * 8; }
            int r = r0 + (l >> 3);
            int swz = ((l & 7) * 16) ^ ((r & 7) << 4);
            const u16* src;
            if (c < 16) src = sb + ((size_t)(base + k0 + r) * 8 + h) * 64 + (swz >> 1);
            else        src = sb + (((size_t)b * 8 + h) * 32 + r) * 2048 + k0 + (swz >> 1);
            GL16(src, &db[r0 * 64]);
        }
        __syncthreads();

        // ---- S^T = K @ Q^T: ta[cj][r] = S[k = cj*16+lg*4+r][q = l15] ----
        f32x4 ta[4] = {{0.f,0.f,0.f,0.f},{0.f,0.f,0.f,0.f},{0.f,0.f,0.f,0.f},{0.f,0.f,0.f,0.f}};
        #pragma unroll
        for (int s = 0; s < 2; ++s) {
            int byo = s * 64 + lg * 16;
            #pragma unroll
            for (int cj = 0; cj < 4; ++cj) {
                bf16x8 kh = *(const bf16x8*)((const char*)KH + swzb(cj * 16 + l15, byo));
                bf16x8 kl = *(const bf16x8*)((const char*)KL + swzb(cj * 16 + l15, byo));
                ta[cj] = MFMA16(kh, qh[s], ta[cj]);
                ta[cj] = MFMA16(kh, ql[s], ta[cj]);
                ta[cj] = MFMA16(kl, qh[s], ta[cj]);
            }
        }

        // ---- lane-local softmax: in-reg tree over 16 + 2 shfl_xor ----
        float t0 = fmaxf(fmaxf(ta[0][0], ta[0][1]), fmaxf(ta[0][2], ta[0][3]));
        float t1 = fmaxf(fmaxf(ta[1][0], ta[1][1]), fmaxf(ta[1][2], ta[1][3]));
        float t2 = fmaxf(fmaxf(ta[2][0], ta[2][1]), fmaxf(ta[2][2], ta[2][3]));
        float t3 = fmaxf(fmaxf(ta[3][0], ta[3][1]), fmaxf(ta[3][2], ta[3][3]));
        float tmax = fmaxf(fmaxf(t0, t1), fmaxf(t2, t3));
        tmax = fmaxf(tmax, __shfl_xor(tmax, 16));
        tmax = fmaxf(tmax, __shfl_xor(tmax, 32));
        float mnew = fmaxf(m_i, tmax);
        float scl = __expf(m_i - mnew);
        #pragma unroll
        for (int cj = 0; cj < 4; ++cj)
            #pragma unroll
            for (int r = 0; r < 4; ++r)
                ta[cj][r] = __expf(ta[cj][r] - mnew);
        float s0 = (ta[0][0] + ta[0][1]) + (ta[0][2] + ta[0][3]);
        float s1 = (ta[1][0] + ta[1][1]) + (ta[1][2] + ta[1][3]);
        float s2 = (ta[2][0] + ta[2][1]) + (ta[2][2] + ta[2][3]);
        float s3 = (ta[3][0] + ta[3][1]) + (ta[3][2] + ta[3][3]);
        float tsum = (s0 + s1) + (s2 + s3);
        tsum += __shfl_xor(tsum, 16);
        tsum += __shfl_xor(tsum, 32);
        l_i = l_i * scl + tsum;
        m_i = mnew;

        // ---- pack P (hi only) -> per-wave LDS: 4 x ds_write_b64 ----
        #pragma unroll
        for (int cj = 0; cj < 4; ++cj) {
            uint2 v = {pkbf2(ta[cj][0], ta[cj][1]), pkbf2(ta[cj][2], ta[cj][3])};
            *(uint2*)((char*)PH[w] + swzb(l15, cj * 32 + lg * 8)) = v;
        }

        // ---- rescale O rows (row q = lg*4+r needs scl from lane lg*4+r) ----
        #pragma unroll
        for (int r = 0; r < 4; ++r) {
            float fac = __shfl(scl, lg * 4 + r);
            o0[r] *= fac;
            o1[r] *= fac;
        }

        // ---- O += P @ V (16q x 32d): P hi x (V hi + V lo) ----
        #pragma unroll
        for (int kq = 0; kq < 2; ++kq) {
            int byo = kq * 64 + lg * 16;
            bf16x8 pa  = *(const bf16x8*)((const char*)PH[w] + swzb(l15, byo));
            bf16x8 vh0 = *(const bf16x8*)((const char*)VH + swzb(l15, byo));
            bf16x8 vl0 = *(const bf16x8*)((const char*)VL + swzb(l15, byo));
            bf16x8 vh1 = *(const bf16x8*)((const char*)VH + swzb(16 + l15, byo));
            bf16x8 vl1 = *(const bf16x8*)((const char*)VL + swzb(16 + l15, byo));
            o0 = MFMA16(pa, vh0, o0);
            o0 = MFMA16(pa, vl0, o0);
            o1 = MFMA16(pa, vh1, o1);
            o1 = MFMA16(pa, vl1, o1);
        }
    }

    // ---- epilogue: write unnormalized partial O + (m,l) ----
    const int pb = (b * 8 + h) * 4 + ks;
    #pragma unroll
    for (int r = 0; r < 4; ++r) {
        int row = q0 + lg * 4 + r;
        size_t ob = ((size_t)pb * 2048 + row) * 32;
        Opart[ob + l15]      = o0[r];
        Opart[ob + 16 + l15] = o1[r];
    }
    if (l < 16) {
        int row = q0 + l15;
        float2 ml = {m_i, l_i};
        *(float2*)&Oml[((size_t)pb * 2048 + row) * 2] = ml;
    }
}

// ---------------------------------------------------------------------------
// Merge 4 k-split partials -> normalized ctx (split bf16).
// grid (64, 8, 2), 256 thr.
// ---------------------------------------------------------------------------
__global__ __launch_bounds__(256) void attn_merge(
    const float* __restrict__ Opart, const float* __restrict__ Oml,
    u16* __restrict__ Cx_hi, u16* __restrict__ Cx_lo)
{
    const int t = threadIdx.x;
    const int d = t & 31, rg = t >> 5;
    const int h = blockIdx.y, b = blockIdx.z;
    const int pb = (b * 8 + h) * 4;
    #pragma unroll
    for (int rr = 0; rr < 4; ++rr) {
        int row = blockIdx.x * 32 + rr * 8 + rg;
        float m[4], lv[4];
        #pragma unroll
        for (int i = 0; i < 4; ++i) {
            size_t mb = ((size_t)(pb + i) * 2048 + row) * 2;
            m[i]  = Oml[mb];
            lv[i] = Oml[mb + 1];
        }
        float M = fmaxf(fmaxf(m[0], m[1]), fmaxf(m[2], m[3]));
        float wgt[4], L = 0.f;
        #pragma unroll
        for (int i = 0; i < 4; ++i) { wgt[i] = __expf(m[i] - M); L += lv[i] * wgt[i]; }
        float o = 0.f;
        #pragma unroll
        for (int i = 0; i < 4; ++i)
            o += wgt[i] * Opart[((size_t)(pb + i) * 2048 + row) * 32 + d];
        float y = o / L;
        u32 hb = bf16rne(y);
        size_t orow = (size_t)(b * 2048 + row) * 256 + h * 32 + d;
        Cx_hi[orow] = (u16)hb;
        Cx_lo[orow] = (u16)bf16rne(y - bf16tof(hb));
    }
}

// ---------------------------------------------------------------------------
// Final GEMM: out = ctx @ Wo + bo, split-bf16 3-MFMA. grid (4, 64).
// ---------------------------------------------------------------------------
__global__ __launch_bounds__(256, 2) void gemm_out_mfma(
    const u16* __restrict__ Xhi, const u16* __restrict__ Xlo,
    const u16* __restrict__ Wth, const u16* __restrict__ Wtl,
    const float* __restrict__ bias, float* __restrict__ out)
{
    __shared__ u16 XH[64 * 64], XL[64 * 64], WH[64 * 64], WL[64 * 64];
    const int t = threadIdx.x, w = t >> 6, l = t & 63;
    const int l15 = l & 15, lg = l >> 4;
    const int bn = blockIdx.x * 64, bm = blockIdx.y * 64;

    const u16* srole = (w == 0) ? Xhi : (w == 1) ? Xlo : (w == 2) ? Wth : Wtl;
    u16* drole = (w == 0) ? XH : (w == 1) ? XL : (w == 2) ? WH : WL;
    const int rbase = (w < 2) ? bm : bn;

    f32x4 acc[4] = {{0.f,0.f,0.f,0.f},{0.f,0.f,0.f,0.f},{0.f,0.f,0.f,0.f},{0.f,0.f,0.f,0.f}};

    for (int k0 = 0; k0 < 256; k0 += 64) {
        __syncthreads();
        #pragma unroll
        for (int c = 0; c < 8; ++c) {
            int r = c * 8 + (l >> 3);
            int swz = ((l & 7) * 16) ^ ((r & 7) << 4);
            const u16* src = srole + (size_t)(rbase + r) * 256 + k0 + (swz >> 1);
            GL16(src, &drole[c * 8 * 64]);
        }
        __syncthreads();
        #pragma unroll
        for (int s = 0; s < 2; ++s) {
            int byo = s * 64 + lg * 16;
            bf16x8 ah = *(const bf16x8*)((const char*)XH + swzb(w * 16 + l15, byo));
            bf16x8 al = *(const bf16x8*)((const char*)XL + swzb(w * 16 + l15, byo));
            #pragma unroll
            for (int cj = 0; cj < 4; ++cj) {
                bf16x8 bh = *(const bf16x8*)((const char*)WH + swzb(cj * 16 + l15, byo));
                bf16x8 bl = *(const bf16x8*)((const char*)WL + swzb(cj * 16 + l15, byo));
                acc[cj] = MFMA16(ah, bh, acc[cj]);
                acc[cj] = MFMA16(al, bh, acc[cj]);
                acc[cj] = MFMA16(ah, bl, acc[cj]);
            }
        }
    }

    #pragma unroll
    for (int cj = 0; cj < 4; ++cj) {
        float bv = bias[bn + cj * 16 + l15];
        #pragma unroll
        for (int r = 0; r < 4; ++r) {
            int row = bm + w * 16 + lg * 4 + r;
            out[(size_t)row * 256 + bn + cj * 16 + l15] = acc[cj][r] + bv;
        }
    }
}

// ---------------------------------------------------------------------------
extern "C" void kernel_launch(void* const* d_in, const int* in_sizes, int n_in,
                              void* d_out, int out_size, void* d_ws, size_t ws_size,
                              hipStream_t stream) {
    const float* A     = (const float*)d_in[0];
    const float* B     = (const float*)d_in[1];
    const float* Wq_aa = (const float*)d_in[2];
    const float* bq_aa = (const float*)d_in[3];
    const float* Wk_aa = (const float*)d_in[4];
    const float* bk_aa = (const float*)d_in[5];
    const float* Wv_a  = (const float*)d_in[6];
    const float* bv_a  = (const float*)d_in[7];
    const float* Wk_ab = (const float*)d_in[8];
    const float* bk_ab = (const float*)d_in[9];
    const float* Wq_bb = (const float*)d_in[10];
    const float* bq_bb = (const float*)d_in[11];
    const float* Wo    = (const float*)d_in[12];
    const float* bo    = (const float*)d_in[13];
    float* out = (float*)d_out;

    char* p = (char*)d_ws;
    u16* Ahi = (u16*)p; p += 6291456;
    u16* Alo = (u16*)p; p += 6291456;
    u16* Bhi = (u16*)p; p += 6291456;
    u16* Blo = (u16*)p; p += 6291456;
    u16* W5t_hi = (u16*)p; p += 1966080;
    u16* W5t_lo = (u16*)p; p += 1966080;
    u16* Wot_hi = (u16*)p; p += 131072;
    u16* Wot_lo = (u16*)p; p += 131072;
    u16* Qpk_hi = (u16*)p; p += 4194304;
    u16* Qpk_lo = (u16*)p; p += 4194304;
    u16* Kpk_hi = (u16*)p; p += 4194304;
    u16* Kpk_lo = (u16*)p; p += 4194304;
    u16* Vt_hi  = (u16*)p; p += 2097152;
    u16* Vt_lo  = (u16*)p; p += 2097152;
    u16* Cx_hi  = (u16*)p; p += 2097152;
    u16* Cx_lo  = (u16*)p; p += 2097152;

    // k-split partials alias the A/B conversion buffers (dead after proj5):
    // Opart 64*2048*32*4 = 16.78 MB, Oml 64*2048*2*4 = 1.05 MB  (< 25.1 MB region)
    float* Opart = (float*)d_ws;
    float* Oml   = (float*)((char*)d_ws + 16777216);

    conv_ab<<<dim3(3072, 2), 256, 0, stream>>>(A, B, Ahi, Alo, Bhi, Blo);
    conv_w<<<dim3(12, 4, 6), 256, 0, stream>>>(Wq_aa, Wk_aa, Wv_a, Wk_ab, Wq_bb, Wo,
                                               W5t_hi, W5t_lo, Wot_hi, Wot_lo);
    proj5_mfma<<<dim3(20, 64), 256, 0, stream>>>(Ahi, Alo, Bhi, Blo, W5t_hi, W5t_lo,
                                                 bq_aa, bk_aa, bv_a, bk_ab, bq_bb,
                                                 Qpk_hi, Qpk_lo, Kpk_hi, Kpk_lo, Vt_hi, Vt_lo);
    attn_mfma4<<<dim3(32, 8, 8), 256, 0, stream>>>(Qpk_hi, Qpk_lo, Kpk_hi, Kpk_lo,
                                                   Vt_hi, Vt_lo, Opart, Oml);
    attn_merge<<<dim3(64, 8, 2), 256, 0, stream>>>(Opart, Oml, Cx_hi, Cx_lo);
    gemm_out_mfma<<<dim3(4, 64), 256, 0, stream>>>(Cx_hi, Cx_lo, Wot_hi, Wot_lo, bo, out);
}

// Round 6
// 115.572 us; speedup vs baseline: 6.3632x; 1.0874x over previous
//
#include <hip/hip_runtime.h>
#include <hip/hip_bf16.h>
#include <math.h>

#define SCALE  0.17677669529663687f            // 1/sqrt(32)
#define QSCALE 0.25501817444361255f            // SCALE * log2(e)  (exp2 domain)

#if __has_builtin(__builtin_amdgcn_exp2f)
#define EXP2(x) __builtin_amdgcn_exp2f(x)
#else
#define EXP2(x) exp2f(x)
#endif

typedef __attribute__((ext_vector_type(8))) short bf16x8;
typedef __attribute__((ext_vector_type(4))) float f32x4;
typedef unsigned int u32;
typedef unsigned short u16;

#define MFMA16(a, b, c) __builtin_amdgcn_mfma_f32_16x16x32_bf16(a, b, c, 0, 0, 0)

__device__ inline u32 bf16rne(float x) {
    u32 u = __float_as_uint(x);
    return (u + 0x7FFFu + ((u >> 16) & 1u)) >> 16;
}
__device__ inline float bf16tof(u32 h) { return __uint_as_float(h << 16); }
// pack 2 floats -> 2 bf16 (RNE) in one u32 (lo = a)
__device__ inline u32 pkbf2(float a, float b) {
    union { __hip_bfloat162 h; u32 u; } cv;
    cv.h = __float22bfloat162_rn(make_float2(a, b));
    return cv.u;
}
// byte addr within a tile of 128-byte rows, XOR-swizzled (G4 / T2)
__device__ inline int swzb(int row, int b) { return row * 128 + (b ^ ((row & 7) << 4)); }

typedef __attribute__((address_space(1))) const u32 gu32;
typedef __attribute__((address_space(3))) u32 lu32;
#define GL16(g, l) __builtin_amdgcn_global_load_lds((gu32*)(const void*)(g), (lu32*)(void*)(l), 16, 0, 0)

// ---------------------------------------------------------------------------
// Convert A and B (fp32 [4096][768]) to split hi/lo bf16.
// ---------------------------------------------------------------------------
__global__ __launch_bounds__(256) void conv_ab(
    const float* __restrict__ A, const float* __restrict__ B,
    u16* __restrict__ Ahi, u16* __restrict__ Alo,
    u16* __restrict__ Bhi, u16* __restrict__ Blo)
{
    const float* src = blockIdx.y ? B : A;
    u16* dh = blockIdx.y ? Bhi : Ahi;
    u16* dl = blockIdx.y ? Blo : Alo;
    size_t i = ((size_t)blockIdx.x * 256 + threadIdx.x) * 4;
    float4 f = *(const float4*)&src[i];
    u32 h0 = bf16rne(f.x), h1 = bf16rne(f.y), h2 = bf16rne(f.z), h3 = bf16rne(f.w);
    ushort4 hv = {(u16)h0, (u16)h1, (u16)h2, (u16)h3};
    ushort4 lv = {(u16)bf16rne(f.x - bf16tof(h0)), (u16)bf16rne(f.y - bf16tof(h1)),
                  (u16)bf16rne(f.z - bf16tof(h2)), (u16)bf16rne(f.w - bf16tof(h3))};
    *(ushort4*)&dh[i] = hv;
    *(ushort4*)&dl[i] = lv;
}

// ---------------------------------------------------------------------------
// Convert + transpose weights: g<5: W[768][256] -> Wt[g][256][768] hi/lo;
// g==5: Wo[256][256] -> Wot[256][256] hi/lo.  grid (12, 4, 6), 256 thr.
// ---------------------------------------------------------------------------
__global__ __launch_bounds__(256) void conv_w(
    const float* __restrict__ W0, const float* __restrict__ W1,
    const float* __restrict__ W2, const float* __restrict__ W3,
    const float* __restrict__ W4, const float* __restrict__ Wo,
    u16* __restrict__ W5t_hi, u16* __restrict__ W5t_lo,
    u16* __restrict__ Wot_hi, u16* __restrict__ Wot_lo)
{
    const int g = blockIdx.z;
    const float* W; int K; u16 *dh, *dl;
    switch (g) {
        case 0: W = W0; K = 768; dh = W5t_hi;              dl = W5t_lo;              break;
        case 1: W = W1; K = 768; dh = W5t_hi + 196608;     dl = W5t_lo + 196608;     break;
        case 2: W = W2; K = 768; dh = W5t_hi + 2 * 196608; dl = W5t_lo + 2 * 196608; break;
        case 3: W = W3; K = 768; dh = W5t_hi + 3 * 196608; dl = W5t_lo + 3 * 196608; break;
        case 4: W = W4; K = 768; dh = W5t_hi + 4 * 196608; dl = W5t_lo + 4 * 196608; break;
        default: W = Wo; K = 256; dh = Wot_hi; dl = Wot_lo; break;
    }
    const int k0 = blockIdx.x * 64, n0 = blockIdx.y * 64;
    if (k0 >= K) return;
    __shared__ float T[64][65];
    const int t = threadIdx.x;
    #pragma unroll
    for (int rep = 0; rep < 4; ++rep) {
        int kr = rep * 16 + (t >> 4);
        int nc = (t & 15) * 4;
        float4 f = *(const float4*)&W[(size_t)(k0 + kr) * 256 + n0 + nc];
        T[kr][nc] = f.x; T[kr][nc + 1] = f.y; T[kr][nc + 2] = f.z; T[kr][nc + 3] = f.w;
    }
    __syncthreads();
    #pragma unroll
    for (int rep = 0; rep < 4; ++rep) {
        int idx = rep * 256 + t;
        int n = idx >> 4, kq = (idx & 15) * 4;
        ushort4 hv, lv;
        float v0 = T[kq + 0][n], v1 = T[kq + 1][n], v2 = T[kq + 2][n], v3 = T[kq + 3][n];
        u32 h0 = bf16rne(v0), h1 = bf16rne(v1), h2 = bf16rne(v2), h3 = bf16rne(v3);
        hv = {(u16)h0, (u16)h1, (u16)h2, (u16)h3};
        lv = {(u16)bf16rne(v0 - bf16tof(h0)), (u16)bf16rne(v1 - bf16tof(h1)),
              (u16)bf16rne(v2 - bf16tof(h2)), (u16)bf16rne(v3 - bf16tof(h3))};
        size_t o = (size_t)(n0 + n) * K + k0 + kq;
        *(ushort4*)&dh[o] = hv;
        *(ushort4*)&dl[o] = lv;
    }
}

// ---------------------------------------------------------------------------
// 5-way projection, split-bf16 3-MFMA. grid (20, 64).
//  g0: Q_self -> Qpk[row][h][d] (QSCALE folded) g3: Q_cross-> Qpk[..][32+d]
//  g1: K_self -> Kpk[row][h][d]                 g4: K_cross-> Kpk[..][32+d]
//  g2: V      -> Vt[b][h][d][k]  (LDS-transposed epilogue)
// Staging descriptors hoisted out of the K-loop.
// ---------------------------------------------------------------------------
__global__ __launch_bounds__(256, 2) void proj5_mfma(
    const u16* __restrict__ Ahi, const u16* __restrict__ Alo,
    const u16* __restrict__ Bhi, const u16* __restrict__ Blo,
    const u16* __restrict__ W5t_hi, const u16* __restrict__ W5t_lo,
    const float* __restrict__ b0, const float* __restrict__ b1,
    const float* __restrict__ b2, const float* __restrict__ b3,
    const float* __restrict__ b4,
    u16* __restrict__ Qpk_hi, u16* __restrict__ Qpk_lo,
    u16* __restrict__ Kpk_hi, u16* __restrict__ Kpk_lo,
    u16* __restrict__ Vt_hi,  u16* __restrict__ Vt_lo)
{
    __shared__ u16 XH[64 * 64], XL[64 * 64], WH[64 * 64], WL[64 * 64];

    const int t = threadIdx.x, w = t >> 6, l = t & 63;
    const int l15 = l & 15, lg = l >> 4;
    const int g  = blockIdx.x >> 2;
    const int bn = (blockIdx.x & 3) * 64;
    const int bm = blockIdx.y * 64;

    const u16* Xhi = (g == 4) ? Bhi : Ahi;
    const u16* Xlo = (g == 4) ? Blo : Alo;
    const u16* Wh  = W5t_hi + (size_t)g * 196608;
    const u16* Wl  = W5t_lo + (size_t)g * 196608;
    const float* bias;
    switch (g) {
        case 0: bias = b0; break;
        case 1: bias = b1; break;
        case 2: bias = b2; break;
        case 3: bias = b3; break;
        default: bias = b4; break;
    }

    const u16* srole = (w == 0) ? Xhi : (w == 1) ? Xlo : (w == 2) ? Wh : Wl;
    u16* drole = (w == 0) ? XH : (w == 1) ? XL : (w == 2) ? WH : WL;
    const int rbase = (w < 2) ? bm : bn;

    // hoisted staging pointers (advance 64 u16 per K-step)
    const u16* sp[8];
    #pragma unroll
    for (int c = 0; c < 8; ++c) {
        int r = c * 8 + (l >> 3);
        int swz = ((l & 7) * 16) ^ ((r & 7) << 4);
        sp[c] = srole + (size_t)(rbase + r) * 768 + (swz >> 1);
    }

    f32x4 acc[4] = {{0.f,0.f,0.f,0.f},{0.f,0.f,0.f,0.f},{0.f,0.f,0.f,0.f},{0.f,0.f,0.f,0.f}};

    for (int k0 = 0; k0 < 768; k0 += 64) {
        __syncthreads();
        #pragma unroll
        for (int c = 0; c < 8; ++c) { GL16(sp[c], &drole[c * 512]); sp[c] += 64; }
        __syncthreads();
        #pragma unroll
        for (int s = 0; s < 2; ++s) {
            int byo = s * 64 + lg * 16;
            bf16x8 ah = *(const bf16x8*)((const char*)XH + swzb(w * 16 + l15, byo));
            bf16x8 al = *(const bf16x8*)((const char*)XL + swzb(w * 16 + l15, byo));
            #pragma unroll
            for (int cj = 0; cj < 4; ++cj) {
                bf16x8 bh = *(const bf16x8*)((const char*)WH + swzb(cj * 16 + l15, byo));
                bf16x8 bl = *(const bf16x8*)((const char*)WL + swzb(cj * 16 + l15, byo));
                acc[cj] = MFMA16(ah, bh, acc[cj]);
                acc[cj] = MFMA16(al, bh, acc[cj]);
                acc[cj] = MFMA16(ah, bl, acc[cj]);
            }
        }
    }

    float biasv[4];
    #pragma unroll
    for (int cj = 0; cj < 4; ++cj) biasv[cj] = bias[bn + cj * 16 + l15];

    if (g != 2) {
        u16* Dh = (g == 0 || g == 3) ? Qpk_hi : Kpk_hi;
        u16* Dl = (g == 0 || g == 3) ? Qpk_lo : Kpk_lo;
        const int dofs = (g == 3 || g == 4) ? 32 : 0;
        const bool scl = (g == 0 || g == 3);
        #pragma unroll
        for (int cj = 0; cj < 4; ++cj) {
            int c = bn + cj * 16 + l15;
            int h = c >> 5, d = (c & 31) + dofs;
            #pragma unroll
            for (int r = 0; r < 4; ++r) {
                int row = bm + w * 16 + lg * 4 + r;
                float y = acc[cj][r] + biasv[cj];
                if (scl) y *= QSCALE;       // exp2-domain logits
                u32 hb = bf16rne(y);
                size_t o = ((size_t)row * 8 + h) * 64 + d;
                Dh[o] = (u16)hb;
                Dl[o] = (u16)bf16rne(y - bf16tof(hb));
            }
        }
    } else {
        __syncthreads();
        #pragma unroll
        for (int cj = 0; cj < 4; ++cj) {
            int dl = cj * 16 + l15;
            #pragma unroll
            for (int r = 0; r < 4; ++r) {
                int kl = w * 16 + lg * 4 + r;
                float y = acc[cj][r] + biasv[cj];
                u32 hb = bf16rne(y);
                int byo = (2 * kl) ^ ((dl & 7) << 4);
                *(u16*)((char*)XH + dl * 128 + byo) = (u16)hb;
                *(u16*)((char*)XL + dl * 128 + byo) = (u16)bf16rne(y - bf16tof(hb));
            }
        }
        __syncthreads();
        const int b = bm >> 11, kb = bm & 2047;
        #pragma unroll
        for (int rep = 0; rep < 4; ++rep) {
            int idx = rep * 256 + t;
            int dl = idx >> 4, kq = idx & 15;
            int c = bn + dl;
            int h = c >> 5, d = c & 31;
            int byo = (8 * kq) ^ ((dl & 7) << 4);
            ushort4 hv = *(const ushort4*)((const char*)XH + dl * 128 + byo);
            ushort4 lv = *(const ushort4*)((const char*)XL + dl * 128 + byo);
            size_t o = (((size_t)b * 8 + h) * 32 + d) * 2048 + kb + kq * 4;
            *(ushort4*)&Vt_hi[o] = hv;
            *(ushort4*)&Vt_lo[o] = lv;
        }
    }
}

// ---------------------------------------------------------------------------
// MFMA flash attention v5: swapped QK^T (lane-local softmax), exp2 domain,
// defer-max (THR=8), hoisted staging, P hi-only, 4-way k-split.
// grid (32, 8, 8): z = b*4+ks. LDS = 32 KB -> 5 blocks/CU.
// ---------------------------------------------------------------------------
__global__ __launch_bounds__(256, 5) void attn_mfma5(
    const u16* __restrict__ Qpk_hi, const u16* __restrict__ Qpk_lo,
    const u16* __restrict__ Kpk_hi, const u16* __restrict__ Kpk_lo,
    const u16* __restrict__ Vt_hi,  const u16* __restrict__ Vt_lo,
    float* __restrict__ Opart, float* __restrict__ Oml)
{
    __shared__ u16 KH[64 * 64], KL[64 * 64], VH[32 * 64], VL[32 * 64];
    __shared__ u16 PH[4][16 * 64];

    const int t = threadIdx.x, w = t >> 6, l = t & 63;
    const int l15 = l & 15, lg = l >> 4;
    const int z = blockIdx.z;
    const int b = z >> 2, ks = z & 3;
    const int h = blockIdx.y;
    const int q0 = blockIdx.x * 64 + w * 16;
    const int base = b * 2048;

    // Q fragments (QSCALE pre-folded)
    bf16x8 qh[2], ql[2];
    {
        size_t ro = ((size_t)(base + q0 + l15) * 8 + h) * 64;
        #pragma unroll
        for (int s = 0; s < 2; ++s) {
            qh[s] = *(const bf16x8*)&Qpk_hi[ro + s * 32 + lg * 8];
            ql[s] = *(const bf16x8*)&Qpk_lo[ro + s * 32 + lg * 8];
        }
    }

    // ---- hoisted staging descriptors: wave w owns chunks c = w, w+4, ... ----
    const u16* sp[6]; u16* dp[6]; int sstep[6];
    {
        const int k00 = ks * 512;
        #pragma unroll
        for (int i = 0; i < 6; ++i) {
            int c = w + i * 4;
            const u16* sb; u16* db; int r0;
            if (c < 8)       { sb = Kpk_hi; db = KH; r0 = c * 8; }
            else if (c < 16) { sb = Kpk_lo; db = KL; r0 = (c - 8) * 8; }
            else if (c < 20) { sb = Vt_hi;  db = VH; r0 = (c - 16) * 8; }
            else             { sb = Vt_lo;  db = VL; r0 = (c - 20) * 8; }
            int r = r0 + (l >> 3);
            int swz = ((l & 7) * 16) ^ ((r & 7) << 4);
            if (c < 16) { sp[i] = sb + ((size_t)(base + k00 + r) * 8 + h) * 64 + (swz >> 1); sstep[i] = 32768; }
            else        { sp[i] = sb + (((size_t)b * 8 + h) * 32 + r) * 2048 + k00 + (swz >> 1); sstep[i] = 64; }
            dp[i] = &db[r0 * 64];
        }
    }

    float m_i = -INFINITY, l_i = 0.f;   // per-lane, q = l15 (x4 replicas), log2 domain
    f32x4 o0 = {0.f, 0.f, 0.f, 0.f}, o1 = {0.f, 0.f, 0.f, 0.f};

    for (int it = 0; it < 8; ++it) {
        __syncthreads();
        #pragma unroll
        for (int i = 0; i < 6; ++i) { GL16(sp[i], dp[i]); sp[i] += sstep[i]; }
        __syncthreads();

        // ---- S^T = K @ Q^T: ta[cj][r] = S[k = cj*16+lg*4+r][q = l15] ----
        f32x4 ta[4] = {{0.f,0.f,0.f,0.f},{0.f,0.f,0.f,0.f},{0.f,0.f,0.f,0.f},{0.f,0.f,0.f,0.f}};
        #pragma unroll
        for (int s = 0; s < 2; ++s) {
            int byo = s * 64 + lg * 16;
            #pragma unroll
            for (int cj = 0; cj < 4; ++cj) {
                bf16x8 kh = *(const bf16x8*)((const char*)KH + swzb(cj * 16 + l15, byo));
                bf16x8 kl = *(const bf16x8*)((const char*)KL + swzb(cj * 16 + l15, byo));
                ta[cj] = MFMA16(kh, qh[s], ta[cj]);
                ta[cj] = MFMA16(kh, ql[s], ta[cj]);
                ta[cj] = MFMA16(kl, qh[s], ta[cj]);
            }
        }

        // ---- lane-local softmax (log2 domain), defer-max THR=8 ----
        float t0 = fmaxf(fmaxf(ta[0][0], ta[0][1]), fmaxf(ta[0][2], ta[0][3]));
        float t1 = fmaxf(fmaxf(ta[1][0], ta[1][1]), fmaxf(ta[1][2], ta[1][3]));
        float t2 = fmaxf(fmaxf(ta[2][0], ta[2][1]), fmaxf(ta[2][2], ta[2][3]));
        float t3 = fmaxf(fmaxf(ta[3][0], ta[3][1]), fmaxf(ta[3][2], ta[3][3]));
        float tmax = fmaxf(fmaxf(t0, t1), fmaxf(t2, t3));
        tmax = fmaxf(tmax, __shfl_xor(tmax, 16));
        tmax = fmaxf(tmax, __shfl_xor(tmax, 32));
        if (!__all(tmax <= m_i + 8.0f)) {
            float mnew = fmaxf(m_i, tmax);
            float sc = EXP2(m_i - mnew);
            l_i *= sc;
            #pragma unroll
            for (int r = 0; r < 4; ++r) {
                float fac = __shfl(sc, lg * 4 + r);
                o0[r] *= fac;
                o1[r] *= fac;
            }
            m_i = mnew;
        }
        #pragma unroll
        for (int cj = 0; cj < 4; ++cj)
            #pragma unroll
            for (int r = 0; r < 4; ++r)
                ta[cj][r] = EXP2(ta[cj][r] - m_i);
        float s0 = (ta[0][0] + ta[0][1]) + (ta[0][2] + ta[0][3]);
        float s1 = (ta[1][0] + ta[1][1]) + (ta[1][2] + ta[1][3]);
        float s2 = (ta[2][0] + ta[2][1]) + (ta[2][2] + ta[2][3]);
        float s3 = (ta[3][0] + ta[3][1]) + (ta[3][2] + ta[3][3]);
        float tsum = (s0 + s1) + (s2 + s3);
        tsum += __shfl_xor(tsum, 16);
        tsum += __shfl_xor(tsum, 32);
        l_i += tsum;

        // ---- pack P (hi only) -> per-wave LDS: 4 x ds_write_b64 ----
        #pragma unroll
        for (int cj = 0; cj < 4; ++cj) {
            uint2 v = {pkbf2(ta[cj][0], ta[cj][1]), pkbf2(ta[cj][2], ta[cj][3])};
            *(uint2*)((char*)PH[w] + swzb(l15, cj * 32 + lg * 8)) = v;
        }

        // ---- O += P @ V (16q x 32d): P hi x (V hi + V lo) ----
        #pragma unroll
        for (int kq = 0; kq < 2; ++kq) {
            int byo = kq * 64 + lg * 16;
            bf16x8 pa  = *(const bf16x8*)((const char*)PH[w] + swzb(l15, byo));
            bf16x8 vh0 = *(const bf16x8*)((const char*)VH + swzb(l15, byo));
            bf16x8 vl0 = *(const bf16x8*)((const char*)VL + swzb(l15, byo));
            bf16x8 vh1 = *(const bf16x8*)((const char*)VH + swzb(16 + l15, byo));
            bf16x8 vl1 = *(const bf16x8*)((const char*)VL + swzb(16 + l15, byo));
            o0 = MFMA16(pa, vh0, o0);
            o0 = MFMA16(pa, vl0, o0);
            o1 = MFMA16(pa, vh1, o1);
            o1 = MFMA16(pa, vl1, o1);
        }
    }

    // ---- epilogue: write unnormalized partial O + (m,l) ----
    const int pb = (b * 8 + h) * 4 + ks;
    #pragma unroll
    for (int r = 0; r < 4; ++r) {
        int row = q0 + lg * 4 + r;
        size_t ob = ((size_t)pb * 2048 + row) * 32;
        Opart[ob + l15]      = o0[r];
        Opart[ob + 16 + l15] = o1[r];
    }
    if (l < 16) {
        int row = q0 + l15;
        float2 ml = {m_i, l_i};
        *(float2*)&Oml[((size_t)pb * 2048 + row) * 2] = ml;
    }
}

// ---------------------------------------------------------------------------
// Merge 4 k-split partials -> normalized ctx (split bf16). m is log2-domain.
// grid (64, 8, 2), 256 thr.
// ---------------------------------------------------------------------------
__global__ __launch_bounds__(256) void attn_merge(
    const float* __restrict__ Opart, const float* __restrict__ Oml,
    u16* __restrict__ Cx_hi, u16* __restrict__ Cx_lo)
{
    const int t = threadIdx.x;
    const int d = t & 31, rg = t >> 5;
    const int h = blockIdx.y, b = blockIdx.z;
    const int pb = (b * 8 + h) * 4;
    #pragma unroll
    for (int rr = 0; rr < 4; ++rr) {
        int row = blockIdx.x * 32 + rr * 8 + rg;
        float m[4], lv[4];
        #pragma unroll
        for (int i = 0; i < 4; ++i) {
            size_t mb = ((size_t)(pb + i) * 2048 + row) * 2;
            m[i]  = Oml[mb];
            lv[i] = Oml[mb + 1];
        }
        float M = fmaxf(fmaxf(m[0], m[1]), fmaxf(m[2], m[3]));
        float wgt[4], L = 0.f;
        #pragma unroll
        for (int i = 0; i < 4; ++i) { wgt[i] = exp2f(m[i] - M); L += lv[i] * wgt[i]; }
        float o = 0.f;
        #pragma unroll
        for (int i = 0; i < 4; ++i)
            o += wgt[i] * Opart[((size_t)(pb + i) * 2048 + row) * 32 + d];
        float y = o / L;
        u32 hb = bf16rne(y);
        size_t orow = (size_t)(b * 2048 + row) * 256 + h * 32 + d;
        Cx_hi[orow] = (u16)hb;
        Cx_lo[orow] = (u16)bf16rne(y - bf16tof(hb));
    }
}

// ---------------------------------------------------------------------------
// Final GEMM: out = ctx @ Wo + bo, split-bf16 3-MFMA. grid (4, 64).
// ---------------------------------------------------------------------------
__global__ __launch_bounds__(256, 2) void gemm_out_mfma(
    const u16* __restrict__ Xhi, const u16* __restrict__ Xlo,
    const u16* __restrict__ Wth, const u16* __restrict__ Wtl,
    const float* __restrict__ bias, float* __restrict__ out)
{
    __shared__ u16 XH[64 * 64], XL[64 * 64], WH[64 * 64], WL[64 * 64];
    const int t = threadIdx.x, w = t >> 6, l = t & 63;
    const int l15 = l & 15, lg = l >> 4;
    const int bn = blockIdx.x * 64, bm = blockIdx.y * 64;

    const u16* srole = (w == 0) ? Xhi : (w == 1) ? Xlo : (w == 2) ? Wth : Wtl;
    u16* drole = (w == 0) ? XH : (w == 1) ? XL : (w == 2) ? WH : WL;
    const int rbase = (w < 2) ? bm : bn;

    const u16* sp[8];
    #pragma unroll
    for (int c = 0; c < 8; ++c) {
        int r = c * 8 + (l >> 3);
        int swz = ((l & 7) * 16) ^ ((r & 7) << 4);
        sp[c] = srole + (size_t)(rbase + r) * 256 + (swz >> 1);
    }

    f32x4 acc[4] = {{0.f,0.f,0.f,0.f},{0.f,0.f,0.f,0.f},{0.f,0.f,0.f,0.f},{0.f,0.f,0.f,0.f}};

    for (int k0 = 0; k0 < 256; k0 += 64) {
        __syncthreads();
        #pragma unroll
        for (int c = 0; c < 8; ++c) { GL16(sp[c], &drole[c * 512]); sp[c] += 64; }
        __syncthreads();
        #pragma unroll
        for (int s = 0; s < 2; ++s) {
            int byo = s * 64 + lg * 16;
            bf16x8 ah = *(const bf16x8*)((const char*)XH + swzb(w * 16 + l15, byo));
            bf16x8 al = *(const bf16x8*)((const char*)XL + swzb(w * 16 + l15, byo));
            #pragma unroll
            for (int cj = 0; cj < 4; ++cj) {
                bf16x8 bh = *(const bf16x8*)((const char*)WH + swzb(cj * 16 + l15, byo));
                bf16x8 bl = *(const bf16x8*)((const char*)WL + swzb(cj * 16 + l15, byo));
                acc[cj] = MFMA16(ah, bh, acc[cj]);
                acc[cj] = MFMA16(al, bh, acc[cj]);
                acc[cj] = MFMA16(ah, bl, acc[cj]);
            }
        }
    }

    #pragma unroll
    for (int cj = 0; cj < 4; ++cj) {
        float bv = bias[bn + cj * 16 + l15];
        #pragma unroll
        for (int r = 0; r < 4; ++r) {
            int row = bm + w * 16 + lg * 4 + r;
            out[(size_t)row * 256 + bn + cj * 16 + l15] = acc[cj][r] + bv;
        }
    }
}

// ---------------------------------------------------------------------------
extern "C" void kernel_launch(void* const* d_in, const int* in_sizes, int n_in,
                              void* d_out, int out_size, void* d_ws, size_t ws_size,
                              hipStream_t stream) {
    const float* A     = (const float*)d_in[0];
    const float* B     = (const float*)d_in[1];
    const float* Wq_aa = (const float*)d_in[2];
    const float* bq_aa = (const float*)d_in[3];
    const float* Wk_aa = (const float*)d_in[4];
    const float* bk_aa = (const float*)d_in[5];
    const float* Wv_a  = (const float*)d_in[6];
    const float* bv_a  = (const float*)d_in[7];
    const float* Wk_ab = (const float*)d_in[8];
    const float* bk_ab = (const float*)d_in[9];
    const float* Wq_bb = (const float*)d_in[10];
    const float* bq_bb = (const float*)d_in[11];
    const float* Wo    = (const float*)d_in[12];
    const float* bo    = (const float*)d_in[13];
    float* out = (float*)d_out;

    char* p = (char*)d_ws;
    u16* Ahi = (u16*)p; p += 6291456;
    u16* Alo = (u16*)p; p += 6291456;
    u16* Bhi = (u16*)p; p += 6291456;
    u16* Blo = (u16*)p; p += 6291456;
    u16* W5t_hi = (u16*)p; p += 1966080;
    u16* W5t_lo = (u16*)p; p += 1966080;
    u16* Wot_hi = (u16*)p; p += 131072;
    u16* Wot_lo = (u16*)p; p += 131072;
    u16* Qpk_hi = (u16*)p; p += 4194304;
    u16* Qpk_lo = (u16*)p; p += 4194304;
    u16* Kpk_hi = (u16*)p; p += 4194304;
    u16* Kpk_lo = (u16*)p; p += 4194304;
    u16* Vt_hi  = (u16*)p; p += 2097152;
    u16* Vt_lo  = (u16*)p; p += 2097152;
    u16* Cx_hi  = (u16*)p; p += 2097152;
    u16* Cx_lo  = (u16*)p; p += 2097152;

    // k-split partials alias the A/B conversion buffers (dead after proj5):
    // Opart 64*2048*32*4 = 16.78 MB, Oml 64*2048*2*4 = 1.05 MB  (< 25.1 MB region)
    float* Opart = (float*)d_ws;
    float* Oml   = (float*)((char*)d_ws + 16777216);

    conv_ab<<<dim3(3072, 2), 256, 0, stream>>>(A, B, Ahi, Alo, Bhi, Blo);
    conv_w<<<dim3(12, 4, 6), 256, 0, stream>>>(Wq_aa, Wk_aa, Wv_a, Wk_ab, Wq_bb, Wo,
                                               W5t_hi, W5t_lo, Wot_hi, Wot_lo);
    proj5_mfma<<<dim3(20, 64), 256, 0, stream>>>(Ahi, Alo, Bhi, Blo, W5t_hi, W5t_lo,
                                                 bq_aa, bk_aa, bv_a, bk_ab, bq_bb,
                                                 Qpk_hi, Qpk_lo, Kpk_hi, Kpk_lo, Vt_hi, Vt_lo);
    attn_mfma5<<<dim3(32, 8, 8), 256, 0, stream>>>(Qpk_hi, Qpk_lo, Kpk_hi, Kpk_lo,
                                                   Vt_hi, Vt_lo, Opart, Oml);
    attn_merge<<<dim3(64, 8, 2), 256, 0, stream>>>(Opart, Oml, Cx_hi, Cx_lo);
    gemm_out_mfma<<<dim3(4, 64), 256, 0, stream>>>(Cx_hi, Cx_lo, Wot_hi, Wot_lo, bo, out);
}